// Round 2
// baseline (3268.880 us; speedup 1.0000x reference)
//
#include <hip/hip_runtime.h>

#define D 128
#define TR 64
#define XS_STRIDE 132   // 128 + 4 pad; row stride 528B keeps 16B alignment

__device__ __forceinline__ float silu_f(float x) {
    return x / (1.0f + __expf(-x));
}

// ---------------- MLP: out = silu(in @ Wa + ba) @ Wb + bb ----------------
// GATHER: input row j = in[src[2j]] * in[src[2j+1]] (elementwise, segment_prod of 2)
template<bool GATHER>
__launch_bounds__(256, 4)
__global__ void mlp_kernel(const float* __restrict__ in,
                           const int* __restrict__ src,
                           const float* __restrict__ Wa, const float* __restrict__ ba,
                           const float* __restrict__ Wb, const float* __restrict__ bb,
                           float* __restrict__ out, int nrows)
{
    __shared__ float xs[TR][XS_STRIDE];
    const int t = threadIdx.x;
    const int row0 = blockIdx.x * TR;

    // ---- stage A: load TR rows into LDS ----
    {
        const int r = t >> 2;       // 0..63
        const int s = t & 3;
        const int row = row0 + r;
        if (row < nrows) {
            if (GATHER) {
                const int a = src[2 * row];
                const int b = src[2 * row + 1];
                const float4* pa = (const float4*)(in + (size_t)a * D);
                const float4* pb = (const float4*)(in + (size_t)b * D);
                #pragma unroll
                for (int i = 0; i < 8; ++i) {
                    const int f = s + 4 * i;
                    float4 va = pa[f], vb = pb[f];
                    *(float4*)&xs[r][4 * f] =
                        make_float4(va.x * vb.x, va.y * vb.y, va.z * vb.z, va.w * vb.w);
                }
            } else {
                const float4* p = (const float4*)(in + (size_t)row * D);
                #pragma unroll
                for (int i = 0; i < 8; ++i) {
                    const int f = s + 4 * i;
                    *(float4*)&xs[r][4 * f] = p[f];
                }
            }
        } else {
            #pragma unroll
            for (int i = 0; i < 8; ++i) {
                const int f = s + 4 * i;
                *(float4*)&xs[r][4 * f] = make_float4(0.f, 0.f, 0.f, 0.f);
            }
        }
    }
    __syncthreads();

    const int c  = (t & 31) * 4;   // 4 output cols
    const int r0 = (t >> 5) * 8;   // 8 rows

    float acc[8][4];

    // ---- stage B: y = silu(x @ Wa + ba) ----
    {
        float4 bias = *(const float4*)&ba[c];
        #pragma unroll
        for (int i = 0; i < 8; ++i) {
            acc[i][0] = bias.x; acc[i][1] = bias.y; acc[i][2] = bias.z; acc[i][3] = bias.w;
        }
        #pragma unroll 2
        for (int k = 0; k < D; k += 4) {
            float4 w0 = *(const float4*)&Wa[(size_t)(k + 0) * D + c];
            float4 w1 = *(const float4*)&Wa[(size_t)(k + 1) * D + c];
            float4 w2 = *(const float4*)&Wa[(size_t)(k + 2) * D + c];
            float4 w3 = *(const float4*)&Wa[(size_t)(k + 3) * D + c];
            #pragma unroll
            for (int i = 0; i < 8; ++i) {
                float4 x4 = *(const float4*)&xs[r0 + i][k];
                acc[i][0] += x4.x * w0.x + x4.y * w1.x + x4.z * w2.x + x4.w * w3.x;
                acc[i][1] += x4.x * w0.y + x4.y * w1.y + x4.z * w2.y + x4.w * w3.y;
                acc[i][2] += x4.x * w0.z + x4.y * w1.z + x4.z * w2.z + x4.w * w3.z;
                acc[i][3] += x4.x * w0.w + x4.y * w1.w + x4.z * w2.w + x4.w * w3.w;
            }
        }
    }
    __syncthreads();
    #pragma unroll
    for (int i = 0; i < 8; ++i) {
        *(float4*)&xs[r0 + i][c] = make_float4(silu_f(acc[i][0]), silu_f(acc[i][1]),
                                               silu_f(acc[i][2]), silu_f(acc[i][3]));
    }
    __syncthreads();

    // ---- stage C: z = y @ Wb + bb ----
    {
        float4 bias = *(const float4*)&bb[c];
        #pragma unroll
        for (int i = 0; i < 8; ++i) {
            acc[i][0] = bias.x; acc[i][1] = bias.y; acc[i][2] = bias.z; acc[i][3] = bias.w;
        }
        #pragma unroll 2
        for (int k = 0; k < D; k += 4) {
            float4 w0 = *(const float4*)&Wb[(size_t)(k + 0) * D + c];
            float4 w1 = *(const float4*)&Wb[(size_t)(k + 1) * D + c];
            float4 w2 = *(const float4*)&Wb[(size_t)(k + 2) * D + c];
            float4 w3 = *(const float4*)&Wb[(size_t)(k + 3) * D + c];
            #pragma unroll
            for (int i = 0; i < 8; ++i) {
                float4 x4 = *(const float4*)&xs[r0 + i][k];
                acc[i][0] += x4.x * w0.x + x4.y * w1.x + x4.z * w2.x + x4.w * w3.x;
                acc[i][1] += x4.x * w0.y + x4.y * w1.y + x4.z * w2.y + x4.w * w3.y;
                acc[i][2] += x4.x * w0.z + x4.y * w1.z + x4.z * w2.z + x4.w * w3.z;
                acc[i][3] += x4.x * w0.w + x4.y * w1.w + x4.z * w2.w + x4.w * w3.w;
            }
        }
    }
    #pragma unroll
    for (int i = 0; i < 8; ++i) {
        const int row = row0 + r0 + i;
        if (row < nrows) {
            *(float4*)(out + (size_t)row * D + c) =
                make_float4(acc[i][0], acc[i][1], acc[i][2], acc[i][3]);
        }
    }
}

// ---- h3_dn[a] += h3t[a]*h3t[b]; h3_dn[b] += h3t[a]*h3t[b]  (h4 on the fly) ----
__global__ void prod_scatter2_kernel(const float* __restrict__ h,
                                     const int* __restrict__ src,
                                     float* __restrict__ acc, int nseg)
{
    const int g = blockIdx.x * blockDim.x + threadIdx.x;
    const int j = g >> 5;
    if (j >= nseg) return;
    const int c = (g & 31) * 4;
    const int a = src[2 * j], b = src[2 * j + 1];
    const float4 va = *(const float4*)(h + (size_t)a * D + c);
    const float4 vb = *(const float4*)(h + (size_t)b * D + c);
    const float4 p = make_float4(va.x * vb.x, va.y * vb.y, va.z * vb.z, va.w * vb.w);
    float* pa = acc + (size_t)a * D + c;
    float* pb = acc + (size_t)b * D + c;
    atomicAdd(pa + 0, p.x); atomicAdd(pa + 1, p.y); atomicAdd(pa + 2, p.z); atomicAdd(pa + 3, p.w);
    atomicAdd(pb + 0, p.x); atomicAdd(pb + 1, p.y); atomicAdd(pb + 2, p.z); atomicAdd(pb + 3, p.w);
}

// ---- acc[idx[e]] += val[e>>1]  over e in [0, nedges) ----
__global__ void gather_scatter_add_kernel(const float* __restrict__ val,
                                          const int* __restrict__ idx,
                                          float* __restrict__ acc, int nedges)
{
    const int g = blockIdx.x * blockDim.x + threadIdx.x;
    const int e = g >> 5;
    if (e >= nedges) return;
    const int c = (g & 31) * 4;
    const int i = idx[e];
    const float4 v = *(const float4*)(val + (size_t)(e >> 1) * D + c);
    float* pd = acc + (size_t)i * D + c;
    atomicAdd(pd + 0, v.x); atomicAdd(pd + 1, v.y); atomicAdd(pd + 2, v.z); atomicAdd(pd + 3, v.w);
}

// ---- hdown[src[e]] += h2dn[e>>1];  h2on1[src[e]] += h2t[e>>1]  (fused, same idx) ----
__global__ void down_fuse_kernel(const float* __restrict__ h2dn,
                                 const float* __restrict__ h2t,
                                 const int* __restrict__ src,
                                 float* __restrict__ hdown,
                                 float* __restrict__ h2on1, int nedges)
{
    const int g = blockIdx.x * blockDim.x + threadIdx.x;
    const int e = g >> 5;
    if (e >= nedges) return;
    const int c = (g & 31) * 4;
    const int i = src[e];
    const int j = e >> 1;
    const float4 vd = *(const float4*)(h2dn + (size_t)j * D + c);
    const float4 vt = *(const float4*)(h2t + (size_t)j * D + c);
    float* p1 = hdown + (size_t)i * D + c;
    float* p2 = h2on1 + (size_t)i * D + c;
    atomicAdd(p1 + 0, vd.x); atomicAdd(p1 + 1, vd.y); atomicAdd(p1 + 2, vd.z); atomicAdd(p1 + 3, vd.w);
    atomicAdd(p2 + 0, vt.x); atomicAdd(p2 + 1, vt.y); atomicAdd(p2 + 2, vt.z); atomicAdd(p2 + 3, vt.w);
}

// ---- out = silu(concat(h1, h2on1, hdown) @ Wo + bo); h1 aliases out (in-place, row-private) ----
__launch_bounds__(256, 4)
__global__ void out_kernel(const float* __restrict__ h1,
                           const float* __restrict__ h2on1,
                           const float* __restrict__ hdown,
                           const float* __restrict__ Wo, const float* __restrict__ bo,
                           float* __restrict__ out, int nrows)
{
    __shared__ float xs[TR][XS_STRIDE];
    const int t = threadIdx.x;
    const int row0 = blockIdx.x * TR;
    const int c  = (t & 31) * 4;
    const int r0 = (t >> 5) * 8;

    float acc[8][4];
    {
        float4 bias = *(const float4*)&bo[c];
        #pragma unroll
        for (int i = 0; i < 8; ++i) {
            acc[i][0] = bias.x; acc[i][1] = bias.y; acc[i][2] = bias.z; acc[i][3] = bias.w;
        }
    }

    const float* parts[3] = {h1, h2on1, hdown};
    #pragma unroll
    for (int p = 0; p < 3; ++p) {
        __syncthreads();
        {
            const int r = t >> 2;
            const int s = t & 3;
            const int row = row0 + r;
            if (row < nrows) {
                const float4* pp = (const float4*)(parts[p] + (size_t)row * D);
                #pragma unroll
                for (int i = 0; i < 8; ++i) {
                    const int f = s + 4 * i;
                    *(float4*)&xs[r][4 * f] = pp[f];
                }
            } else {
                #pragma unroll
                for (int i = 0; i < 8; ++i) {
                    const int f = s + 4 * i;
                    *(float4*)&xs[r][4 * f] = make_float4(0.f, 0.f, 0.f, 0.f);
                }
            }
        }
        __syncthreads();
        const float* W = Wo + (size_t)p * D * D;   // Wo is [384][128] row-major
        #pragma unroll 2
        for (int k = 0; k < D; k += 4) {
            float4 w0 = *(const float4*)&W[(size_t)(k + 0) * D + c];
            float4 w1 = *(const float4*)&W[(size_t)(k + 1) * D + c];
            float4 w2 = *(const float4*)&W[(size_t)(k + 2) * D + c];
            float4 w3 = *(const float4*)&W[(size_t)(k + 3) * D + c];
            #pragma unroll
            for (int i = 0; i < 8; ++i) {
                float4 x4 = *(const float4*)&xs[r0 + i][k];
                acc[i][0] += x4.x * w0.x + x4.y * w1.x + x4.z * w2.x + x4.w * w3.x;
                acc[i][1] += x4.x * w0.y + x4.y * w1.y + x4.z * w2.y + x4.w * w3.y;
                acc[i][2] += x4.x * w0.z + x4.y * w1.z + x4.z * w2.z + x4.w * w3.z;
                acc[i][3] += x4.x * w0.w + x4.y * w1.w + x4.z * w2.w + x4.w * w3.w;
            }
        }
    }

    #pragma unroll
    for (int i = 0; i < 8; ++i) {
        const int row = row0 + r0 + i;
        if (row < nrows) {
            *(float4*)(out + (size_t)row * D + c) =
                make_float4(silu_f(acc[i][0]), silu_f(acc[i][1]),
                            silu_f(acc[i][2]), silu_f(acc[i][3]));
        }
    }
}

// diagnostic: if workspace too small, report its size via d_out[0]
__global__ void ws_report_kernel(float* out, float v) {
    if (threadIdx.x == 0 && blockIdx.x == 0) out[0] = v;
}

extern "C" void kernel_launch(void* const* d_in, const int* in_sizes, int n_in,
                              void* d_out, int out_size, void* d_ws, size_t ws_size,
                              hipStream_t stream)
{
    const float* feat = (const float*)d_in[0];
    const float* W1a = (const float*)d_in[1];  const float* b1a = (const float*)d_in[2];
    const float* W1b = (const float*)d_in[3];  const float* b1b = (const float*)d_in[4];
    const float* W2a = (const float*)d_in[5];  const float* b2a = (const float*)d_in[6];
    const float* W2b = (const float*)d_in[7];  const float* b2b = (const float*)d_in[8];
    const float* W3a = (const float*)d_in[9];  const float* b3a = (const float*)d_in[10];
    const float* W3b = (const float*)d_in[11]; const float* b3b = (const float*)d_in[12];
    const float* Wo  = (const float*)d_in[13]; const float* bo  = (const float*)d_in[14];
    const int* src12 = (const int*)d_in[15];
    const int* src23 = (const int*)d_in[17];
    const int* src34 = (const int*)d_in[19];

    const int N1 = in_sizes[0] / D;
    const int N2 = in_sizes[15] / 2;
    const int N3 = in_sizes[17] / 2;
    const int N4 = in_sizes[19] / 2;

    // workspace layout (floats):
    //   A = ws[0 .. N3*D)            : h3dn; later hdown = A[0..N1*D), h2on1 = A[N1*D..2*N1*D)
    //   B = ws[N3*D .. N3*D+N2*D)    : h2t
    //   C = ws[N3*D+N2*D .. +N3*D)   : h3t; later h2dn = C[0..N2*D)
    // h1 lives in d_out (same size as output; out_kernel reads/writes row-private).
    const size_t need = ((size_t)N2 + 2 * (size_t)N3) * D * sizeof(float);
    if (ws_size < need) {
        ws_report_kernel<<<1, 64, 0, stream>>>((float*)d_out, (float)ws_size);
        return;
    }

    float* ws    = (float*)d_ws;
    float* h3dn  = ws;
    float* h2t   = ws + (size_t)N3 * D;
    float* h3t   = h2t + (size_t)N2 * D;
    float* h2dn  = h3t;                      // alias (h3t dead after prod_scatter2)
    float* hdown = h3dn;                     // alias (h3dn dead after gather_scatter)
    float* h2on1 = h3dn + (size_t)N1 * D;    // alias (N3 >= 2*N1)
    float* h1    = (float*)d_out;

    dim3 blk(256);
    auto tiles = [](int n) { return dim3((unsigned)((n + TR - 1) / TR)); };

    // upward
    mlp_kernel<false><<<tiles(N1), blk, 0, stream>>>(feat, nullptr, W1a, b1a, W1b, b1b, h1, N1);
    mlp_kernel<true ><<<tiles(N2), blk, 0, stream>>>(h1, src12, W2a, b2a, W2b, b2b, h2t, N2);
    mlp_kernel<true ><<<tiles(N3), blk, 0, stream>>>(h2t, src23, W3a, b3a, W3b, b3b, h3t, N3);

    // downward
    hipMemsetAsync(h3dn, 0, (size_t)N3 * D * sizeof(float), stream);
    {
        const long long th = (long long)N4 * 32;
        prod_scatter2_kernel<<<dim3((unsigned)((th + 255) / 256)), blk, 0, stream>>>(h3t, src34, h3dn, N4);
    }
    hipMemsetAsync(h2dn, 0, (size_t)N2 * D * sizeof(float), stream);
    {
        const long long th = (long long)2 * N3 * 32;
        gather_scatter_add_kernel<<<dim3((unsigned)((th + 255) / 256)), blk, 0, stream>>>(h3dn, src23, h2dn, 2 * N3);
    }
    hipMemsetAsync(hdown, 0, (size_t)2 * N1 * D * sizeof(float), stream);
    {
        const long long th = (long long)2 * N2 * 32;
        down_fuse_kernel<<<dim3((unsigned)((th + 255) / 256)), blk, 0, stream>>>(h2dn, h2t, src12, hdown, h2on1, 2 * N2);
    }

    // final fused concat-linear + SiLU (h1 in d_out, overwritten row-private)
    out_kernel<<<tiles(N1), blk, 0, stream>>>(h1, h2on1, hdown, Wo, bo, (float*)d_out, N1);
}

// Round 3
// 914.260 us; speedup vs baseline: 3.5754x; 3.5754x over previous
//
#include <hip/hip_runtime.h>

#define D 128
#define TR 64
#define XS_STRIDE 132   // 128 + 4 pad
#define SCAN_T 512

__device__ __forceinline__ float silu_f(float x) {
    return x / (1.0f + __expf(-x));
}

// ---------------- MLP: out = silu(in @ Wa + ba) @ Wb + bb ----------------
template<bool GATHER>
__launch_bounds__(256, 4)
__global__ void mlp_kernel(const float* __restrict__ in,
                           const int* __restrict__ src,
                           const float* __restrict__ Wa, const float* __restrict__ ba,
                           const float* __restrict__ Wb, const float* __restrict__ bb,
                           float* __restrict__ out, int nrows)
{
    __shared__ float xs[TR][XS_STRIDE];
    const int t = threadIdx.x;
    const int row0 = blockIdx.x * TR;

    {
        const int r = t >> 2;
        const int s = t & 3;
        const int row = row0 + r;
        if (row < nrows) {
            if (GATHER) {
                const int a = src[2 * row];
                const int b = src[2 * row + 1];
                const float4* pa = (const float4*)(in + (size_t)a * D);
                const float4* pb = (const float4*)(in + (size_t)b * D);
                #pragma unroll
                for (int i = 0; i < 8; ++i) {
                    const int f = s + 4 * i;
                    float4 va = pa[f], vb = pb[f];
                    *(float4*)&xs[r][4 * f] =
                        make_float4(va.x * vb.x, va.y * vb.y, va.z * vb.z, va.w * vb.w);
                }
            } else {
                const float4* p = (const float4*)(in + (size_t)row * D);
                #pragma unroll
                for (int i = 0; i < 8; ++i) {
                    const int f = s + 4 * i;
                    *(float4*)&xs[r][4 * f] = p[f];
                }
            }
        } else {
            #pragma unroll
            for (int i = 0; i < 8; ++i) {
                const int f = s + 4 * i;
                *(float4*)&xs[r][4 * f] = make_float4(0.f, 0.f, 0.f, 0.f);
            }
        }
    }
    __syncthreads();

    const int c  = (t & 31) * 4;
    const int r0 = (t >> 5) * 8;

    float acc[8][4];

    { // stage B: y = silu(x @ Wa + ba)
        float4 bias = *(const float4*)&ba[c];
        #pragma unroll
        for (int i = 0; i < 8; ++i) {
            acc[i][0] = bias.x; acc[i][1] = bias.y; acc[i][2] = bias.z; acc[i][3] = bias.w;
        }
        #pragma unroll 2
        for (int k = 0; k < D; k += 4) {
            float4 w0 = *(const float4*)&Wa[(size_t)(k + 0) * D + c];
            float4 w1 = *(const float4*)&Wa[(size_t)(k + 1) * D + c];
            float4 w2 = *(const float4*)&Wa[(size_t)(k + 2) * D + c];
            float4 w3 = *(const float4*)&Wa[(size_t)(k + 3) * D + c];
            #pragma unroll
            for (int i = 0; i < 8; ++i) {
                float4 x4 = *(const float4*)&xs[r0 + i][k];
                acc[i][0] += x4.x * w0.x + x4.y * w1.x + x4.z * w2.x + x4.w * w3.x;
                acc[i][1] += x4.x * w0.y + x4.y * w1.y + x4.z * w2.y + x4.w * w3.y;
                acc[i][2] += x4.x * w0.z + x4.y * w1.z + x4.z * w2.z + x4.w * w3.z;
                acc[i][3] += x4.x * w0.w + x4.y * w1.w + x4.z * w2.w + x4.w * w3.w;
            }
        }
    }
    __syncthreads();
    #pragma unroll
    for (int i = 0; i < 8; ++i) {
        *(float4*)&xs[r0 + i][c] = make_float4(silu_f(acc[i][0]), silu_f(acc[i][1]),
                                               silu_f(acc[i][2]), silu_f(acc[i][3]));
    }
    __syncthreads();

    { // stage C: z = y @ Wb + bb
        float4 bias = *(const float4*)&bb[c];
        #pragma unroll
        for (int i = 0; i < 8; ++i) {
            acc[i][0] = bias.x; acc[i][1] = bias.y; acc[i][2] = bias.z; acc[i][3] = bias.w;
        }
        #pragma unroll 2
        for (int k = 0; k < D; k += 4) {
            float4 w0 = *(const float4*)&Wb[(size_t)(k + 0) * D + c];
            float4 w1 = *(const float4*)&Wb[(size_t)(k + 1) * D + c];
            float4 w2 = *(const float4*)&Wb[(size_t)(k + 2) * D + c];
            float4 w3 = *(const float4*)&Wb[(size_t)(k + 3) * D + c];
            #pragma unroll
            for (int i = 0; i < 8; ++i) {
                float4 x4 = *(const float4*)&xs[r0 + i][k];
                acc[i][0] += x4.x * w0.x + x4.y * w1.x + x4.z * w2.x + x4.w * w3.x;
                acc[i][1] += x4.x * w0.y + x4.y * w1.y + x4.z * w2.y + x4.w * w3.y;
                acc[i][2] += x4.x * w0.z + x4.y * w1.z + x4.z * w2.z + x4.w * w3.z;
                acc[i][3] += x4.x * w0.w + x4.y * w1.w + x4.z * w2.w + x4.w * w3.w;
            }
        }
    }
    #pragma unroll
    for (int i = 0; i < 8; ++i) {
        const int row = row0 + r0 + i;
        if (row < nrows) {
            *(float4*)(out + (size_t)row * D + c) =
                make_float4(acc[i][0], acc[i][1], acc[i][2], acc[i][3]);
        }
    }
}

// ---------------- CSR build: hist -> scan -> fill ----------------
__global__ void hist_kernel(const int* __restrict__ src, int E, int* __restrict__ cnt) {
    const int e = blockIdx.x * blockDim.x + threadIdx.x;
    if (e < E) atomicAdd(&cnt[src[e]], 1);
}

__global__ void scan_reduce_kernel(const int* __restrict__ cnt, int n, int* __restrict__ bsum) {
    __shared__ int s[SCAN_T];
    const int t = threadIdx.x, b = blockIdx.x;
    const int i = b * SCAN_T + t;
    s[t] = (i < n) ? cnt[i] : 0;
    __syncthreads();
    for (int st = SCAN_T / 2; st > 0; st >>= 1) {
        if (t < st) s[t] += s[t + st];
        __syncthreads();
    }
    if (t == 0) bsum[b] = s[0];
}

// single block, exclusive-scans bsum[0..nb) in place (nb <= 1024)
__global__ void scan_top_kernel(int* __restrict__ bsum, int nb) {
    __shared__ int s[1024];
    const int t = threadIdx.x;
    int v = (t < nb) ? bsum[t] : 0;
    s[t] = v;
    __syncthreads();
    for (int off = 1; off < 1024; off <<= 1) {
        int u = (t >= off) ? s[t - off] : 0;
        __syncthreads();
        s[t] += u;
        __syncthreads();
    }
    if (t < nb) bsum[t] = s[t] - v;
}

__global__ void scan_apply_kernel(const int* __restrict__ cnt, int n,
                                  const int* __restrict__ bsum,
                                  int* __restrict__ off, int* __restrict__ cur) {
    __shared__ int s[SCAN_T];
    const int t = threadIdx.x, b = blockIdx.x;
    const int i = b * SCAN_T + t;
    const int v = (i < n) ? cnt[i] : 0;
    s[t] = v;
    __syncthreads();
    for (int o = 1; o < SCAN_T; o <<= 1) {
        int u = (t >= o) ? s[t - o] : 0;
        __syncthreads();
        s[t] += u;
        __syncthreads();
    }
    if (i < n) {
        const int ex = s[t] - v + bsum[b];
        off[i] = ex;
        cur[i] = ex;
    }
}

__global__ void fill_kernel(const int* __restrict__ src, int E,
                            int* __restrict__ cur, int* __restrict__ el) {
    const int e = blockIdx.x * blockDim.x + threadIdx.x;
    if (e < E) {
        const int p = atomicAdd(&cur[src[e]], 1);
        el[p] = e;
    }
}

// ---- h3dn[i] = sum over incoming edges of h3t[i] * h3t[sibling] (h4 on the fly) ----
__global__ void prod_gather_kernel(const float* __restrict__ h3t,
                                   const int* __restrict__ src34,
                                   const int* __restrict__ off, const int* __restrict__ cnt,
                                   const int* __restrict__ el,
                                   float* __restrict__ h3dn, int nrows)
{
    const long long g = (long long)blockIdx.x * blockDim.x + threadIdx.x;
    const int i = (int)(g >> 5);
    if (i >= nrows) return;
    const int c = ((int)g & 31) * 4;
    const float4 own = *(const float4*)(h3t + (size_t)i * D + c);
    float4 acc = make_float4(0.f, 0.f, 0.f, 0.f);
    const int base = off[i], deg = cnt[i];
    for (int d = 0; d < deg; ++d) {
        const int eid = el[base + d];
        const int sib = src34[eid ^ 1];
        const float4 v = *(const float4*)(h3t + (size_t)sib * D + c);
        acc.x += own.x * v.x; acc.y += own.y * v.y;
        acc.z += own.z * v.z; acc.w += own.w * v.w;
    }
    *(float4*)(h3dn + (size_t)i * D + c) = acc;
}

// ---- dst[i] = sum over CSR edges e of val[e>>1] ----
__global__ void gather_sum_kernel(const float* __restrict__ val,
                                  const int* __restrict__ off, const int* __restrict__ cnt,
                                  const int* __restrict__ el,
                                  float* __restrict__ dst, int nrows)
{
    const long long g = (long long)blockIdx.x * blockDim.x + threadIdx.x;
    const int i = (int)(g >> 5);
    if (i >= nrows) return;
    const int c = ((int)g & 31) * 4;
    float4 acc = make_float4(0.f, 0.f, 0.f, 0.f);
    const int base = off[i], deg = cnt[i];
    for (int d = 0; d < deg; ++d) {
        const int j = el[base + d] >> 1;
        const float4 v = *(const float4*)(val + (size_t)j * D + c);
        acc.x += v.x; acc.y += v.y; acc.z += v.z; acc.w += v.w;
    }
    *(float4*)(dst + (size_t)i * D + c) = acc;
}

// ---- out = silu(concat(h1, h2on1, hdown) @ Wo + bo); h1 aliases out ----
__launch_bounds__(256, 4)
__global__ void out_kernel(const float* __restrict__ h1,
                           const float* __restrict__ h2on1,
                           const float* __restrict__ hdown,
                           const float* __restrict__ Wo, const float* __restrict__ bo,
                           float* __restrict__ out, int nrows)
{
    __shared__ float xs[TR][XS_STRIDE];
    const int t = threadIdx.x;
    const int row0 = blockIdx.x * TR;
    const int c  = (t & 31) * 4;
    const int r0 = (t >> 5) * 8;

    float acc[8][4];
    {
        float4 bias = *(const float4*)&bo[c];
        #pragma unroll
        for (int i = 0; i < 8; ++i) {
            acc[i][0] = bias.x; acc[i][1] = bias.y; acc[i][2] = bias.z; acc[i][3] = bias.w;
        }
    }

    const float* parts[3] = {h1, h2on1, hdown};
    #pragma unroll
    for (int p = 0; p < 3; ++p) {
        __syncthreads();
        {
            const int r = t >> 2;
            const int s = t & 3;
            const int row = row0 + r;
            if (row < nrows) {
                const float4* pp = (const float4*)(parts[p] + (size_t)row * D);
                #pragma unroll
                for (int i = 0; i < 8; ++i) {
                    const int f = s + 4 * i;
                    *(float4*)&xs[r][4 * f] = pp[f];
                }
            } else {
                #pragma unroll
                for (int i = 0; i < 8; ++i) {
                    const int f = s + 4 * i;
                    *(float4*)&xs[r][4 * f] = make_float4(0.f, 0.f, 0.f, 0.f);
                }
            }
        }
        __syncthreads();
        const float* W = Wo + (size_t)p * D * D;
        #pragma unroll 2
        for (int k = 0; k < D; k += 4) {
            float4 w0 = *(const float4*)&W[(size_t)(k + 0) * D + c];
            float4 w1 = *(const float4*)&W[(size_t)(k + 1) * D + c];
            float4 w2 = *(const float4*)&W[(size_t)(k + 2) * D + c];
            float4 w3 = *(const float4*)&W[(size_t)(k + 3) * D + c];
            #pragma unroll
            for (int i = 0; i < 8; ++i) {
                float4 x4 = *(const float4*)&xs[r0 + i][k];
                acc[i][0] += x4.x * w0.x + x4.y * w1.x + x4.z * w2.x + x4.w * w3.x;
                acc[i][1] += x4.x * w0.y + x4.y * w1.y + x4.z * w2.y + x4.w * w3.y;
                acc[i][2] += x4.x * w0.z + x4.y * w1.z + x4.z * w2.z + x4.w * w3.z;
                acc[i][3] += x4.x * w0.w + x4.y * w1.w + x4.z * w2.w + x4.w * w3.w;
            }
        }
    }

    #pragma unroll
    for (int i = 0; i < 8; ++i) {
        const int row = row0 + r0 + i;
        if (row < nrows) {
            *(float4*)(out + (size_t)row * D + c) =
                make_float4(silu_f(acc[i][0]), silu_f(acc[i][1]),
                            silu_f(acc[i][2]), silu_f(acc[i][3]));
        }
    }
}

// diagnostic: if workspace too small, report its size via d_out[0]
__global__ void ws_report_kernel(float* out, float v) {
    if (threadIdx.x == 0 && blockIdx.x == 0) out[0] = v;
}

extern "C" void kernel_launch(void* const* d_in, const int* in_sizes, int n_in,
                              void* d_out, int out_size, void* d_ws, size_t ws_size,
                              hipStream_t stream)
{
    const float* feat = (const float*)d_in[0];
    const float* W1a = (const float*)d_in[1];  const float* b1a = (const float*)d_in[2];
    const float* W1b = (const float*)d_in[3];  const float* b1b = (const float*)d_in[4];
    const float* W2a = (const float*)d_in[5];  const float* b2a = (const float*)d_in[6];
    const float* W2b = (const float*)d_in[7];  const float* b2b = (const float*)d_in[8];
    const float* W3a = (const float*)d_in[9];  const float* b3a = (const float*)d_in[10];
    const float* W3b = (const float*)d_in[11]; const float* b3b = (const float*)d_in[12];
    const float* Wo  = (const float*)d_in[13]; const float* bo  = (const float*)d_in[14];
    const int* src12 = (const int*)d_in[15];
    const int* src23 = (const int*)d_in[17];
    const int* src34 = (const int*)d_in[19];

    const int N1 = in_sizes[0] / D;
    const int N2 = in_sizes[15] / 2;
    const int N3 = in_sizes[17] / 2;
    const int N4 = in_sizes[19] / 2;
    const int E12 = 2 * N2, E23 = 2 * N3, E34 = 2 * N4;

    // ---- workspace layout ----
    // floats: [h2on1 N1*D][regB N3*D][regC N3*D]
    //   regB: h3t  -> h2dn        regC: h2t -> h3dn -> hdown
    // ints after floats: CSR12, CSR23, CSR34, bsum
    float* fbase = (float*)d_ws;
    float* h2on1 = fbase;
    float* regB  = fbase + (size_t)N1 * D;
    float* regC  = regB + (size_t)N3 * D;
    float* h3t  = regB;  float* h2dn  = regB;
    float* h2t  = regC;  float* h3dn  = regC;  float* hdown = regC;
    float* h1   = (float*)d_out;

    int* ibase = (int*)(regC + (size_t)N3 * D);
    int* cnt12 = ibase;          int* off12 = cnt12 + N1; int* cur12 = off12 + N1; int* el12 = cur12 + N1;
    int* cnt23 = el12 + E12;     int* off23 = cnt23 + N2; int* cur23 = off23 + N2; int* el23 = cur23 + N2;
    int* cnt34 = el23 + E23;     int* off34 = cnt34 + N3; int* cur34 = off34 + N3; int* el34 = cur34 + N3;
    int* bsum  = el34 + E34;

    const size_t need = (char*)(bsum + 1024) - (char*)d_ws;
    if (ws_size < need) {
        ws_report_kernel<<<1, 64, 0, stream>>>((float*)d_out, (float)ws_size);
        return;
    }

    dim3 blk(256);
    auto tiles  = [](int n) { return dim3((unsigned)((n + TR - 1) / TR)); };
    auto eblk   = [](int e) { return dim3((unsigned)((e + 255) / 256)); };
    auto rowblk = [](long long rows) { return dim3((unsigned)((rows * 32 + 255) / 256)); };

    // ---- build reverse CSRs (int-only work) ----
    hipMemsetAsync(cnt12, 0, (size_t)N1 * sizeof(int), stream);
    hipMemsetAsync(cnt23, 0, (size_t)N2 * sizeof(int), stream);
    hipMemsetAsync(cnt34, 0, (size_t)N3 * sizeof(int), stream);
    hist_kernel<<<eblk(E12), blk, 0, stream>>>(src12, E12, cnt12);
    hist_kernel<<<eblk(E23), blk, 0, stream>>>(src23, E23, cnt23);
    hist_kernel<<<eblk(E34), blk, 0, stream>>>(src34, E34, cnt34);
    auto scan3 = [&](int* cnt, int* off, int* cur, int n) {
        const int nb = (n + SCAN_T - 1) / SCAN_T;
        scan_reduce_kernel<<<dim3((unsigned)nb), dim3(SCAN_T), 0, stream>>>(cnt, n, bsum);
        scan_top_kernel<<<1, 1024, 0, stream>>>(bsum, nb);
        scan_apply_kernel<<<dim3((unsigned)nb), dim3(SCAN_T), 0, stream>>>(cnt, n, bsum, off, cur);
    };
    scan3(cnt12, off12, cur12, N1);
    fill_kernel<<<eblk(E12), blk, 0, stream>>>(src12, E12, cur12, el12);
    scan3(cnt23, off23, cur23, N2);
    fill_kernel<<<eblk(E23), blk, 0, stream>>>(src23, E23, cur23, el23);
    scan3(cnt34, off34, cur34, N3);
    fill_kernel<<<eblk(E34), blk, 0, stream>>>(src34, E34, cur34, el34);

    // ---- upward ----
    mlp_kernel<false><<<tiles(N1), blk, 0, stream>>>(feat, nullptr, W1a, b1a, W1b, b1b, h1, N1);
    mlp_kernel<true ><<<tiles(N2), blk, 0, stream>>>(h1, src12, W2a, b2a, W2b, b2b, h2t, N2);
    // h2on1 early so h2t can die before h3dn lands in regC
    gather_sum_kernel<<<rowblk(N1), blk, 0, stream>>>(h2t, off12, cnt12, el12, h2on1, N1);
    mlp_kernel<true ><<<tiles(N3), blk, 0, stream>>>(h2t, src23, W3a, b3a, W3b, b3b, h3t, N3);

    // ---- downward (all gathers, no float atomics) ----
    prod_gather_kernel<<<rowblk(N3), blk, 0, stream>>>(h3t, src34, off34, cnt34, el34, h3dn, N3);
    gather_sum_kernel<<<rowblk(N2), blk, 0, stream>>>(h3dn, off23, cnt23, el23, h2dn, N2);
    gather_sum_kernel<<<rowblk(N1), blk, 0, stream>>>(h2dn, off12, cnt12, el12, hdown, N1);

    // ---- final fused concat-linear + SiLU ----
    out_kernel<<<tiles(N1), blk, 0, stream>>>(h1, h2on1, hdown, Wo, bo, (float*)d_out, N1);
}

// Round 4
// 722.030 us; speedup vs baseline: 4.5273x; 1.2662x over previous
//
#include <hip/hip_runtime.h>

#define D 128
#define SCAN_T 512
#define XSH 136   // fp16 row stride (272 B): keeps 16B alignment, spreads banks

typedef _Float16 f16;
typedef __attribute__((ext_vector_type(4))) _Float16 f16x4;
typedef __attribute__((ext_vector_type(8))) _Float16 f16x8;
typedef __attribute__((ext_vector_type(4))) float    f32x4;

__device__ __forceinline__ float silu_f(float x) {
    return x / (1.0f + __expf(-x));
}

// ---------------- weight pre-convert: WT[n][k] = (f16) W[k][n] ----------------
__global__ void wconv_kernel(const float* __restrict__ W, f16* __restrict__ WT, int K, int N) {
    const int idx = blockIdx.x * blockDim.x + threadIdx.x;
    if (idx >= N * K) return;
    const int n = idx / K;
    const int k = idx - n * K;
    WT[idx] = (f16)W[(size_t)k * N + n];
}

// ---------------- MLP via MFMA: out = silu(in @ Wa + ba) @ Wb + bb ----------------
// GATHER: input row g = in[src[2g]] * in[src[2g+1]] (segment_prod of 2, fused)
// Block = 256 threads = 4 waves; wave w owns rows [blk*64 + 16w, +16).
// WaT/WbT are fp16, transposed [n][k] (128x128).
template<bool GATHER>
__launch_bounds__(256)
__global__ void mlp_mfma_kernel(const float* __restrict__ in, const int* __restrict__ src,
                                const f16* __restrict__ WaT, const float* __restrict__ ba,
                                const f16* __restrict__ WbT, const float* __restrict__ bb,
                                float* __restrict__ out, int nrows)
{
    __shared__ f16 xs[4][16][XSH];
    const int t = threadIdx.x;
    const int w = t >> 6;          // wave 0..3
    const int l = t & 63;          // lane
    const int row0 = blockIdx.x * 64 + w * 16;

    // ---- stage A: wave stages its own 16 rows (fp32 -> fp16, fused product) ----
    {
        const int r = l >> 2;      // 0..15
        const int q = l & 3;       // 32-col quarter
        const int g = row0 + r;
        f16* dst = &xs[w][r][q * 32];
        if (g < nrows) {
            if (GATHER) {
                const int a = src[2 * g], b = src[2 * g + 1];
                const float4* pa = (const float4*)(in + (size_t)a * D) + q * 8;
                const float4* pb = (const float4*)(in + (size_t)b * D) + q * 8;
                #pragma unroll
                for (int i = 0; i < 8; ++i) {
                    float4 va = pa[i], vb = pb[i];
                    f16x4 hv = {(f16)(va.x * vb.x), (f16)(va.y * vb.y),
                                (f16)(va.z * vb.z), (f16)(va.w * vb.w)};
                    *(f16x4*)(dst + 4 * i) = hv;
                }
            } else {
                const float4* p = (const float4*)(in + (size_t)g * D) + q * 8;
                #pragma unroll
                for (int i = 0; i < 8; ++i) {
                    float4 v = p[i];
                    f16x4 hv = {(f16)v.x, (f16)v.y, (f16)v.z, (f16)v.w};
                    *(f16x4*)(dst + 4 * i) = hv;
                }
            }
        } else {
            f16x4 z = {(f16)0.f, (f16)0.f, (f16)0.f, (f16)0.f};
            #pragma unroll
            for (int i = 0; i < 8; ++i) *(f16x4*)(dst + 4 * i) = z;
        }
    }
    __syncthreads();

    const int cl = l & 15;    // A-row within wave tile / output col within 16-tile
    const int kg = l >> 4;    // k-group 0..3

    f32x4 acc[8];

    // ---- stage B: y = silu(x @ Wa + ba) ----
    #pragma unroll
    for (int n = 0; n < 8; ++n) acc[n] = (f32x4){0.f, 0.f, 0.f, 0.f};
    #pragma unroll
    for (int kk = 0; kk < 4; ++kk) {
        const f16x8 a = *(const f16x8*)&xs[w][cl][kk * 32 + kg * 8];
        #pragma unroll
        for (int n = 0; n < 8; ++n) {
            const f16x8 b = *(const f16x8*)(WaT + (size_t)(n * 16 + cl) * D + kk * 32 + kg * 8);
            acc[n] = __builtin_amdgcn_mfma_f32_16x16x32_f16(a, b, acc[n], 0, 0, 0);
        }
    }
    __syncthreads();
    // epilogue: bias + silu, write y (fp16) back into the wave's own LDS tile.
    // C/D layout (m89-verified): col = n*16 + (lane&15), row = (lane>>4)*4 + reg.
    #pragma unroll
    for (int n = 0; n < 8; ++n) {
        const float bv = ba[n * 16 + cl];
        #pragma unroll
        for (int r2 = 0; r2 < 4; ++r2) {
            xs[w][kg * 4 + r2][n * 16 + cl] = (f16)silu_f(acc[n][r2] + bv);
        }
    }
    __syncthreads();

    // ---- stage C: z = y @ Wb + bb ----
    #pragma unroll
    for (int n = 0; n < 8; ++n) acc[n] = (f32x4){0.f, 0.f, 0.f, 0.f};
    #pragma unroll
    for (int kk = 0; kk < 4; ++kk) {
        const f16x8 a = *(const f16x8*)&xs[w][cl][kk * 32 + kg * 8];
        #pragma unroll
        for (int n = 0; n < 8; ++n) {
            const f16x8 b = *(const f16x8*)(WbT + (size_t)(n * 16 + cl) * D + kk * 32 + kg * 8);
            acc[n] = __builtin_amdgcn_mfma_f32_16x16x32_f16(a, b, acc[n], 0, 0, 0);
        }
    }
    #pragma unroll
    for (int n = 0; n < 8; ++n) {
        const float bv = bb[n * 16 + cl];
        #pragma unroll
        for (int r2 = 0; r2 < 4; ++r2) {
            const int gr = row0 + kg * 4 + r2;
            if (gr < nrows) out[(size_t)gr * D + n * 16 + cl] = acc[n][r2] + bv;
        }
    }
}

// ---------------- final: out = silu(concat(h1,h2on1,hdown) @ Wo + bo) ----------------
// WoT is fp16 [128][384]. h1 aliases out (row-private in-place).
__launch_bounds__(256)
__global__ void out_mfma_kernel(const float* __restrict__ h1, const float* __restrict__ h2on1,
                                const float* __restrict__ hdown,
                                const f16* __restrict__ WoT, const float* __restrict__ bo,
                                float* __restrict__ out, int nrows)
{
    __shared__ f16 xs[4][16][XSH];
    const int t = threadIdx.x;
    const int w = t >> 6;
    const int l = t & 63;
    const int row0 = blockIdx.x * 64 + w * 16;
    const int cl = l & 15;
    const int kg = l >> 4;

    f32x4 acc[8];
    #pragma unroll
    for (int n = 0; n < 8; ++n) acc[n] = (f32x4){0.f, 0.f, 0.f, 0.f};

    const float* parts[3] = {h1, h2on1, hdown};
    #pragma unroll
    for (int p = 0; p < 3; ++p) {
        {   // stage part p rows
            const int r = l >> 2;
            const int q = l & 3;
            const int g = row0 + r;
            f16* dst = &xs[w][r][q * 32];
            if (g < nrows) {
                const float4* pp = (const float4*)(parts[p] + (size_t)g * D) + q * 8;
                #pragma unroll
                for (int i = 0; i < 8; ++i) {
                    float4 v = pp[i];
                    f16x4 hv = {(f16)v.x, (f16)v.y, (f16)v.z, (f16)v.w};
                    *(f16x4*)(dst + 4 * i) = hv;
                }
            } else {
                f16x4 z = {(f16)0.f, (f16)0.f, (f16)0.f, (f16)0.f};
                #pragma unroll
                for (int i = 0; i < 8; ++i) *(f16x4*)(dst + 4 * i) = z;
            }
        }
        __syncthreads();
        #pragma unroll
        for (int kk = 0; kk < 4; ++kk) {
            const f16x8 a = *(const f16x8*)&xs[w][cl][kk * 32 + kg * 8];
            #pragma unroll
            for (int n = 0; n < 8; ++n) {
                const f16x8 b = *(const f16x8*)(WoT + (size_t)(n * 16 + cl) * 384 + p * D + kk * 32 + kg * 8);
                acc[n] = __builtin_amdgcn_mfma_f32_16x16x32_f16(a, b, acc[n], 0, 0, 0);
            }
        }
        __syncthreads();
    }

    #pragma unroll
    for (int n = 0; n < 8; ++n) {
        const float bv = bo[n * 16 + cl];
        #pragma unroll
        for (int r2 = 0; r2 < 4; ++r2) {
            const int gr = row0 + kg * 4 + r2;
            if (gr < nrows) out[(size_t)gr * D + n * 16 + cl] = silu_f(acc[n][r2] + bv);
        }
    }
}

// ---------------- CSR build: hist -> scan -> fill ----------------
__global__ void hist_kernel(const int* __restrict__ src, int E, int* __restrict__ cnt) {
    const int e = blockIdx.x * blockDim.x + threadIdx.x;
    if (e < E) atomicAdd(&cnt[src[e]], 1);
}

__global__ void scan_reduce_kernel(const int* __restrict__ cnt, int n, int* __restrict__ bsum) {
    __shared__ int s[SCAN_T];
    const int t = threadIdx.x, b = blockIdx.x;
    const int i = b * SCAN_T + t;
    s[t] = (i < n) ? cnt[i] : 0;
    __syncthreads();
    for (int st = SCAN_T / 2; st > 0; st >>= 1) {
        if (t < st) s[t] += s[t + st];
        __syncthreads();
    }
    if (t == 0) bsum[b] = s[0];
}

__global__ void scan_top_kernel(int* __restrict__ bsum, int nb) {
    __shared__ int s[1024];
    const int t = threadIdx.x;
    int v = (t < nb) ? bsum[t] : 0;
    s[t] = v;
    __syncthreads();
    for (int off = 1; off < 1024; off <<= 1) {
        int u = (t >= off) ? s[t - off] : 0;
        __syncthreads();
        s[t] += u;
        __syncthreads();
    }
    if (t < nb) bsum[t] = s[t] - v;
}

__global__ void scan_apply_kernel(const int* __restrict__ cnt, int n,
                                  const int* __restrict__ bsum,
                                  int* __restrict__ off, int* __restrict__ cur) {
    __shared__ int s[SCAN_T];
    const int t = threadIdx.x, b = blockIdx.x;
    const int i = b * SCAN_T + t;
    const int v = (i < n) ? cnt[i] : 0;
    s[t] = v;
    __syncthreads();
    for (int o = 1; o < SCAN_T; o <<= 1) {
        int u = (t >= o) ? s[t - o] : 0;
        __syncthreads();
        s[t] += u;
        __syncthreads();
    }
    if (i < n) {
        const int ex = s[t] - v + bsum[b];
        off[i] = ex;
        cur[i] = ex;
    }
}

__global__ void fill_kernel(const int* __restrict__ src, int E,
                            int* __restrict__ cur, int* __restrict__ el) {
    const int e = blockIdx.x * blockDim.x + threadIdx.x;
    if (e < E) {
        const int p = atomicAdd(&cur[src[e]], 1);
        el[p] = e;
    }
}

// ---- h3dn[i] = h3t[i] * sum over incoming edges of h3t[sibling] (h4 on the fly) ----
__global__ void prod_gather_kernel(const float* __restrict__ h3t,
                                   const int* __restrict__ src34,
                                   const int* __restrict__ off, const int* __restrict__ cnt,
                                   const int* __restrict__ el,
                                   float* __restrict__ h3dn, int nrows)
{
    const long long g = (long long)blockIdx.x * blockDim.x + threadIdx.x;
    const int i = (int)(g >> 5);
    if (i >= nrows) return;
    const int c = ((int)g & 31) * 4;
    const float4 own = *(const float4*)(h3t + (size_t)i * D + c);
    float4 acc = make_float4(0.f, 0.f, 0.f, 0.f);
    const int base = off[i], deg = cnt[i];
    for (int d = 0; d < deg; ++d) {
        const int eid = el[base + d];
        const int sib = src34[eid ^ 1];
        const float4 v = *(const float4*)(h3t + (size_t)sib * D + c);
        acc.x += v.x; acc.y += v.y; acc.z += v.z; acc.w += v.w;
    }
    *(float4*)(h3dn + (size_t)i * D + c) =
        make_float4(own.x * acc.x, own.y * acc.y, own.z * acc.z, own.w * acc.w);
}

// ---- dst[i] = sum over CSR edges e of val[e>>1] ----
__global__ void gather_sum_kernel(const float* __restrict__ val,
                                  const int* __restrict__ off, const int* __restrict__ cnt,
                                  const int* __restrict__ el,
                                  float* __restrict__ dst, int nrows)
{
    const long long g = (long long)blockIdx.x * blockDim.x + threadIdx.x;
    const int i = (int)(g >> 5);
    if (i >= nrows) return;
    const int c = ((int)g & 31) * 4;
    float4 acc = make_float4(0.f, 0.f, 0.f, 0.f);
    const int base = off[i], deg = cnt[i];
    for (int d = 0; d < deg; ++d) {
        const int j = el[base + d] >> 1;
        const float4 v = *(const float4*)(val + (size_t)j * D + c);
        acc.x += v.x; acc.y += v.y; acc.z += v.z; acc.w += v.w;
    }
    *(float4*)(dst + (size_t)i * D + c) = acc;
}

// diagnostic: if workspace too small, report its size via d_out[0]
__global__ void ws_report_kernel(float* out, float v) {
    if (threadIdx.x == 0 && blockIdx.x == 0) out[0] = v;
}

extern "C" void kernel_launch(void* const* d_in, const int* in_sizes, int n_in,
                              void* d_out, int out_size, void* d_ws, size_t ws_size,
                              hipStream_t stream)
{
    const float* feat = (const float*)d_in[0];
    const float* W1a = (const float*)d_in[1];  const float* b1a = (const float*)d_in[2];
    const float* W1b = (const float*)d_in[3];  const float* b1b = (const float*)d_in[4];
    const float* W2a = (const float*)d_in[5];  const float* b2a = (const float*)d_in[6];
    const float* W2b = (const float*)d_in[7];  const float* b2b = (const float*)d_in[8];
    const float* W3a = (const float*)d_in[9];  const float* b3a = (const float*)d_in[10];
    const float* W3b = (const float*)d_in[11]; const float* b3b = (const float*)d_in[12];
    const float* Wo  = (const float*)d_in[13]; const float* bo  = (const float*)d_in[14];
    const int* src12 = (const int*)d_in[15];
    const int* src23 = (const int*)d_in[17];
    const int* src34 = (const int*)d_in[19];

    const int N1 = in_sizes[0] / D;
    const int N2 = in_sizes[15] / 2;
    const int N3 = in_sizes[17] / 2;
    const int N4 = in_sizes[19] / 2;
    const int E12 = 2 * N2, E23 = 2 * N3, E34 = 2 * N4;

    // ---- workspace layout ----
    // floats: [h2on1 N1*D][regB N3*D][regC N3*D]
    //   regB: h3t -> h2dn     regC: h2t -> h3dn -> hdown
    // then CSR ints, then fp16 weights.
    float* fbase = (float*)d_ws;
    float* h2on1 = fbase;
    float* regB  = fbase + (size_t)N1 * D;
    float* regC  = regB + (size_t)N3 * D;
    float* h3t  = regB;  float* h2dn  = regB;
    float* h2t  = regC;  float* h3dn  = regC;  float* hdown = regC;
    float* h1   = (float*)d_out;

    int* ibase = (int*)(regC + (size_t)N3 * D);
    int* cnt12 = ibase;          int* off12 = cnt12 + N1; int* cur12 = off12 + N1; int* el12 = cur12 + N1;
    int* cnt23 = el12 + E12;     int* off23 = cnt23 + N2; int* cur23 = off23 + N2; int* el23 = cur23 + N2;
    int* cnt34 = el23 + E23;     int* off34 = cnt34 + N3; int* cur34 = off34 + N3; int* el34 = cur34 + N3;
    int* bsum  = el34 + E34;

    // fp16 weight block, 32B-aligned
    char* wraw = (char*)(bsum + 1024);
    wraw = (char*)(((uintptr_t)wraw + 31) & ~(uintptr_t)31);
    f16* WaT1 = (f16*)wraw;
    f16* WbT1 = WaT1 + D * D;
    f16* WaT2 = WbT1 + D * D;
    f16* WbT2 = WaT2 + D * D;
    f16* WaT3 = WbT2 + D * D;
    f16* WbT3 = WaT3 + D * D;
    f16* WoT  = WbT3 + D * D;   // [128][384]

    const size_t need = (char*)(WoT + 384 * D) - (char*)d_ws;
    if (ws_size < need) {
        ws_report_kernel<<<1, 64, 0, stream>>>((float*)d_out, (float)ws_size);
        return;
    }

    dim3 blk(256);
    auto tiles  = [](int n) { return dim3((unsigned)((n + 63) / 64)); };
    auto eblk   = [](int e) { return dim3((unsigned)((e + 255) / 256)); };
    auto rowblk = [](long long rows) { return dim3((unsigned)((rows * 32 + 255) / 256)); };

    // ---- weight convert (fp16, transposed) ----
    wconv_kernel<<<dim3(64), blk, 0, stream>>>(W1a, WaT1, D, D);
    wconv_kernel<<<dim3(64), blk, 0, stream>>>(W1b, WbT1, D, D);
    wconv_kernel<<<dim3(64), blk, 0, stream>>>(W2a, WaT2, D, D);
    wconv_kernel<<<dim3(64), blk, 0, stream>>>(W2b, WbT2, D, D);
    wconv_kernel<<<dim3(64), blk, 0, stream>>>(W3a, WaT3, D, D);
    wconv_kernel<<<dim3(64), blk, 0, stream>>>(W3b, WbT3, D, D);
    wconv_kernel<<<dim3(192), blk, 0, stream>>>(Wo, WoT, 384, D);

    // ---- build reverse CSRs ----
    hipMemsetAsync(cnt12, 0, (size_t)N1 * sizeof(int), stream);
    hipMemsetAsync(cnt23, 0, (size_t)N2 * sizeof(int), stream);
    hipMemsetAsync(cnt34, 0, (size_t)N3 * sizeof(int), stream);
    hist_kernel<<<eblk(E12), blk, 0, stream>>>(src12, E12, cnt12);
    hist_kernel<<<eblk(E23), blk, 0, stream>>>(src23, E23, cnt23);
    hist_kernel<<<eblk(E34), blk, 0, stream>>>(src34, E34, cnt34);
    auto scan3 = [&](int* cnt, int* off, int* cur, int n) {
        const int nb = (n + SCAN_T - 1) / SCAN_T;
        scan_reduce_kernel<<<dim3((unsigned)nb), dim3(SCAN_T), 0, stream>>>(cnt, n, bsum);
        scan_top_kernel<<<1, 1024, 0, stream>>>(bsum, nb);
        scan_apply_kernel<<<dim3((unsigned)nb), dim3(SCAN_T), 0, stream>>>(cnt, n, bsum, off, cur);
    };
    scan3(cnt12, off12, cur12, N1);
    fill_kernel<<<eblk(E12), blk, 0, stream>>>(src12, E12, cur12, el12);
    scan3(cnt23, off23, cur23, N2);
    fill_kernel<<<eblk(E23), blk, 0, stream>>>(src23, E23, cur23, el23);
    scan3(cnt34, off34, cur34, N3);
    fill_kernel<<<eblk(E34), blk, 0, stream>>>(src34, E34, cur34, el34);

    // ---- upward (MFMA MLPs) ----
    mlp_mfma_kernel<false><<<tiles(N1), blk, 0, stream>>>(feat, nullptr, WaT1, b1a, WbT1, b1b, h1, N1);
    mlp_mfma_kernel<true ><<<tiles(N2), blk, 0, stream>>>(h1, src12, WaT2, b2a, WbT2, b2b, h2t, N2);
    // h2on1 early so h2t can die before h3dn lands in regC
    gather_sum_kernel<<<rowblk(N1), blk, 0, stream>>>(h2t, off12, cnt12, el12, h2on1, N1);
    mlp_mfma_kernel<true ><<<tiles(N3), blk, 0, stream>>>(h2t, src23, WaT3, b3a, WbT3, b3b, h3t, N3);

    // ---- downward (all gathers, no float atomics) ----
    prod_gather_kernel<<<rowblk(N3), blk, 0, stream>>>(h3t, src34, off34, cnt34, el34, h3dn, N3);
    gather_sum_kernel<<<rowblk(N2), blk, 0, stream>>>(h3dn, off23, cnt23, el23, h2dn, N2);
    gather_sum_kernel<<<rowblk(N1), blk, 0, stream>>>(h2dn, off12, cnt12, el12, hdown, N1);

    // ---- final fused concat-linear + SiLU (MFMA) ----
    out_mfma_kernel<<<tiles(N1), blk, 0, stream>>>(h1, h2on1, hdown, WoT, bo, (float*)d_out, N1);
}

// Round 5
// 483.845 us; speedup vs baseline: 6.7561x; 1.4923x over previous
//
#include <hip/hip_runtime.h>

#define D 128
#define SCAN_T 512
#define XSH 136   // f16 row stride (272 B = 16*17): 16B-aligned rows, spreads banks

typedef _Float16 f16;
typedef __attribute__((ext_vector_type(8))) _Float16 f16x8;
typedef __attribute__((ext_vector_type(4))) float    f32x4;

__device__ __forceinline__ float silu_f(float x) {
    return x / (1.0f + __expf(-x));
}

// ---------------- weight pre-convert: WT[n][k] = (f16) W[k][n] ----------------
__global__ void wconv_kernel(const float* __restrict__ W, f16* __restrict__ WT, int K, int N) {
    const int idx = blockIdx.x * blockDim.x + threadIdx.x;
    if (idx >= N * K) return;
    const int n = idx / K;
    const int k = idx - n * K;
    WT[idx] = (f16)W[(size_t)k * N + n];
}

// ---------------- MLP via MFMA: out = silu(in @ Wa + ba) @ Wb + bb ----------------
// Block = 256 thr = 4 waves; block owns 64 rows; wave w owns output cols [32w,32w+32).
// Weight fragments live in registers for the whole block (loaded once).
// GATHER: row g = in16[src[2g]] * in16[src[2g+1]]; else row g = (f16)in32[g].
template<bool GATHER>
__launch_bounds__(256)
__global__ void mlp_mfma_kernel(const void* __restrict__ in_, const int* __restrict__ src,
                                const f16* __restrict__ WaT, const float* __restrict__ ba,
                                const f16* __restrict__ WbT, const float* __restrict__ bb,
                                f16* __restrict__ out, int nrows)
{
    __shared__ f16 xs[64][XSH];
    const int t = threadIdx.x;
    const int w = t >> 6, l = t & 63;
    const int cl = l & 15, kg = l >> 4;
    const int row0 = blockIdx.x * 64;

    // ---- weight fragments -> registers (once per block) ----
    f16x8 wa[2][4], wb[2][4];
    #pragma unroll
    for (int nt = 0; nt < 2; ++nt)
        #pragma unroll
        for (int kk = 0; kk < 4; ++kk) {
            const size_t o = (size_t)((w * 2 + nt) * 16 + cl) * D + kk * 32 + kg * 8;
            wa[nt][kk] = *(const f16x8*)(WaT + o);
            wb[nt][kk] = *(const f16x8*)(WbT + o);
        }

    // ---- stage A: 64 rows -> LDS (f16) ----
    {
        const int r = t >> 2, q = t & 3;
        const int g = row0 + r;
        f16* dst = &xs[r][q * 32];
        if (g < nrows) {
            if (GATHER) {
                const f16* in = (const f16*)in_;
                const int a = src[2 * g], b = src[2 * g + 1];
                const f16x8* pa = (const f16x8*)(in + (size_t)a * D + q * 32);
                const f16x8* pb = (const f16x8*)(in + (size_t)b * D + q * 32);
                #pragma unroll
                for (int i = 0; i < 4; ++i) {
                    f16x8 av = pa[i], bv = pb[i], hv;
                    #pragma unroll
                    for (int j = 0; j < 8; ++j) hv[j] = (f16)((float)av[j] * (float)bv[j]);
                    *(f16x8*)(dst + 8 * i) = hv;
                }
            } else {
                const float* in = (const float*)in_;
                const float4* p = (const float4*)(in + (size_t)g * D + q * 32);
                #pragma unroll
                for (int i = 0; i < 4; ++i) {
                    float4 v0 = p[2 * i], v1 = p[2 * i + 1];
                    f16x8 hv = {(f16)v0.x, (f16)v0.y, (f16)v0.z, (f16)v0.w,
                                (f16)v1.x, (f16)v1.y, (f16)v1.z, (f16)v1.w};
                    *(f16x8*)(dst + 8 * i) = hv;
                }
            }
        } else {
            f16x8 z = {};
            #pragma unroll
            for (int i = 0; i < 4; ++i) *(f16x8*)(dst + 8 * i) = z;
        }
    }
    __syncthreads();

    f32x4 acc[2][4];

    // ---- stage B: y = silu(x @ Wa + ba) ----
    #pragma unroll
    for (int nt = 0; nt < 2; ++nt)
        #pragma unroll
        for (int m = 0; m < 4; ++m) acc[nt][m] = (f32x4){0.f, 0.f, 0.f, 0.f};
    #pragma unroll
    for (int m = 0; m < 4; ++m)
        #pragma unroll
        for (int kk = 0; kk < 4; ++kk) {
            const f16x8 a = *(const f16x8*)&xs[m * 16 + cl][kk * 32 + kg * 8];
            acc[0][m] = __builtin_amdgcn_mfma_f32_16x16x32_f16(a, wa[0][kk], acc[0][m], 0, 0, 0);
            acc[1][m] = __builtin_amdgcn_mfma_f32_16x16x32_f16(a, wa[1][kk], acc[1][m], 0, 0, 0);
        }
    __syncthreads();
    // C/D layout (m89-verified): col = nt*16+cl (within wave's 32-col slice), row = kg*4+r2.
    #pragma unroll
    for (int nt = 0; nt < 2; ++nt) {
        const float bv = ba[w * 32 + nt * 16 + cl];
        #pragma unroll
        for (int m = 0; m < 4; ++m)
            #pragma unroll
            for (int r2 = 0; r2 < 4; ++r2)
                xs[m * 16 + kg * 4 + r2][w * 32 + nt * 16 + cl] = (f16)silu_f(acc[nt][m][r2] + bv);
    }
    __syncthreads();

    // ---- stage C: z = y @ Wb + bb ----
    #pragma unroll
    for (int nt = 0; nt < 2; ++nt)
        #pragma unroll
        for (int m = 0; m < 4; ++m) acc[nt][m] = (f32x4){0.f, 0.f, 0.f, 0.f};
    #pragma unroll
    for (int m = 0; m < 4; ++m)
        #pragma unroll
        for (int kk = 0; kk < 4; ++kk) {
            const f16x8 a = *(const f16x8*)&xs[m * 16 + cl][kk * 32 + kg * 8];
            acc[0][m] = __builtin_amdgcn_mfma_f32_16x16x32_f16(a, wb[0][kk], acc[0][m], 0, 0, 0);
            acc[1][m] = __builtin_amdgcn_mfma_f32_16x16x32_f16(a, wb[1][kk], acc[1][m], 0, 0, 0);
        }
    __syncthreads();
    #pragma unroll
    for (int nt = 0; nt < 2; ++nt) {
        const float bv = bb[w * 32 + nt * 16 + cl];
        #pragma unroll
        for (int m = 0; m < 4; ++m)
            #pragma unroll
            for (int r2 = 0; r2 < 4; ++r2)
                xs[m * 16 + kg * 4 + r2][w * 32 + nt * 16 + cl] = (f16)(acc[nt][m][r2] + bv);
    }
    __syncthreads();

    // ---- coalesced f16 store ----
    {
        const int r = t >> 2, q = t & 3;
        const int g = row0 + r;
        if (g < nrows) {
            f16* dst = out + (size_t)g * D + q * 32;
            #pragma unroll
            for (int i = 0; i < 4; ++i)
                *(f16x8*)(dst + 8 * i) = *(const f16x8*)&xs[r][q * 32 + 8 * i];
        }
    }
}

// ---------------- final: out = silu(concat(h1,h2on1,hdown) @ Wo + bo), fp32 out ----------------
__launch_bounds__(256)
__global__ void out_mfma_kernel(const f16* __restrict__ h1, const f16* __restrict__ h2on1,
                                const f16* __restrict__ hdown,
                                const f16* __restrict__ WoT, const float* __restrict__ bo,
                                float* __restrict__ out, int nrows)
{
    __shared__ f16 xs[64][XSH];
    const int t = threadIdx.x;
    const int w = t >> 6, l = t & 63;
    const int cl = l & 15, kg = l >> 4;
    const int row0 = blockIdx.x * 64;

    f32x4 acc[2][4];
    #pragma unroll
    for (int nt = 0; nt < 2; ++nt)
        #pragma unroll
        for (int m = 0; m < 4; ++m) acc[nt][m] = (f32x4){0.f, 0.f, 0.f, 0.f};

    const f16* parts[3] = {h1, h2on1, hdown};
    #pragma unroll
    for (int p = 0; p < 3; ++p) {
        // weight fragments for this K-segment
        f16x8 wo[2][4];
        #pragma unroll
        for (int nt = 0; nt < 2; ++nt)
            #pragma unroll
            for (int kk = 0; kk < 4; ++kk)
                wo[nt][kk] = *(const f16x8*)(WoT + (size_t)((w * 2 + nt) * 16 + cl) * 384
                                             + p * D + kk * 32 + kg * 8);
        {   // stage part p rows (straight f16 copy)
            const int r = t >> 2, q = t & 3;
            const int g = row0 + r;
            f16* dst = &xs[r][q * 32];
            if (g < nrows) {
                const f16x8* pp = (const f16x8*)(parts[p] + (size_t)g * D + q * 32);
                #pragma unroll
                for (int i = 0; i < 4; ++i) *(f16x8*)(dst + 8 * i) = pp[i];
            } else {
                f16x8 z = {};
                #pragma unroll
                for (int i = 0; i < 4; ++i) *(f16x8*)(dst + 8 * i) = z;
            }
        }
        __syncthreads();
        #pragma unroll
        for (int m = 0; m < 4; ++m)
            #pragma unroll
            for (int kk = 0; kk < 4; ++kk) {
                const f16x8 a = *(const f16x8*)&xs[m * 16 + cl][kk * 32 + kg * 8];
                acc[0][m] = __builtin_amdgcn_mfma_f32_16x16x32_f16(a, wo[0][kk], acc[0][m], 0, 0, 0);
                acc[1][m] = __builtin_amdgcn_mfma_f32_16x16x32_f16(a, wo[1][kk], acc[1][m], 0, 0, 0);
            }
        __syncthreads();
    }

    #pragma unroll
    for (int nt = 0; nt < 2; ++nt) {
        const float bv = bo[w * 32 + nt * 16 + cl];
        #pragma unroll
        for (int m = 0; m < 4; ++m)
            #pragma unroll
            for (int r2 = 0; r2 < 4; ++r2) {
                const int g = row0 + m * 16 + kg * 4 + r2;
                if (g < nrows) out[(size_t)g * D + w * 32 + nt * 16 + cl] = silu_f(acc[nt][m][r2] + bv);
            }
    }
}

// ---------------- CSR build: hist -> scan -> fill ----------------
__global__ void hist_kernel(const int* __restrict__ src, int E, int* __restrict__ cnt) {
    const int e = blockIdx.x * blockDim.x + threadIdx.x;
    if (e < E) atomicAdd(&cnt[src[e]], 1);
}

__global__ void scan_reduce_kernel(const int* __restrict__ cnt, int n, int* __restrict__ bsum) {
    __shared__ int s[SCAN_T];
    const int t = threadIdx.x, b = blockIdx.x;
    const int i = b * SCAN_T + t;
    s[t] = (i < n) ? cnt[i] : 0;
    __syncthreads();
    for (int st = SCAN_T / 2; st > 0; st >>= 1) {
        if (t < st) s[t] += s[t + st];
        __syncthreads();
    }
    if (t == 0) bsum[b] = s[0];
}

__global__ void scan_top_kernel(int* __restrict__ bsum, int nb) {
    __shared__ int s[1024];
    const int t = threadIdx.x;
    int v = (t < nb) ? bsum[t] : 0;
    s[t] = v;
    __syncthreads();
    for (int off = 1; off < 1024; off <<= 1) {
        int u = (t >= off) ? s[t - off] : 0;
        __syncthreads();
        s[t] += u;
        __syncthreads();
    }
    if (t < nb) bsum[t] = s[t] - v;
}

__global__ void scan_apply_kernel(const int* __restrict__ cnt, int n,
                                  const int* __restrict__ bsum,
                                  int* __restrict__ off, int* __restrict__ cur) {
    __shared__ int s[SCAN_T];
    const int t = threadIdx.x, b = blockIdx.x;
    const int i = b * SCAN_T + t;
    const int v = (i < n) ? cnt[i] : 0;
    s[t] = v;
    __syncthreads();
    for (int o = 1; o < SCAN_T; o <<= 1) {
        int u = (t >= o) ? s[t - o] : 0;
        __syncthreads();
        s[t] += u;
        __syncthreads();
    }
    if (i < n) {
        const int ex = s[t] - v + bsum[b];
        off[i] = ex;
        cur[i] = ex;
    }
}

__global__ void fill_kernel(const int* __restrict__ src, int E,
                            int* __restrict__ cur, int* __restrict__ el) {
    const int e = blockIdx.x * blockDim.x + threadIdx.x;
    if (e < E) {
        const int p = atomicAdd(&cur[src[e]], 1);
        el[p] = e;
    }
}

// ---- load/store helpers: 8 contiguous elems <-> float[8] ----
__device__ __forceinline__ void load8(const f16* p, float* a) {
    f16x8 v = *(const f16x8*)p;
    #pragma unroll
    for (int j = 0; j < 8; ++j) a[j] = (float)v[j];
}
__device__ __forceinline__ void load8(const float* p, float* a) {
    float4 v0 = ((const float4*)p)[0], v1 = ((const float4*)p)[1];
    a[0] = v0.x; a[1] = v0.y; a[2] = v0.z; a[3] = v0.w;
    a[4] = v1.x; a[5] = v1.y; a[6] = v1.z; a[7] = v1.w;
}
__device__ __forceinline__ void store8(f16* p, const float* a) {
    f16x8 v;
    #pragma unroll
    for (int j = 0; j < 8; ++j) v[j] = (f16)a[j];
    *(f16x8*)p = v;
}
__device__ __forceinline__ void store8(float* p, const float* a) {
    ((float4*)p)[0] = make_float4(a[0], a[1], a[2], a[3]);
    ((float4*)p)[1] = make_float4(a[4], a[5], a[6], a[7]);
}

// ---- h3dn[i] = h3t[i] * sum of h3t[sibling] over incoming edges (h4 on the fly) ----
__global__ void prod_gather_kernel(const f16* __restrict__ h3t,
                                   const int* __restrict__ src34,
                                   const int* __restrict__ off, const int* __restrict__ cnt,
                                   const int* __restrict__ el,
                                   float* __restrict__ h3dn, int nrows)
{
    const long long g = (long long)blockIdx.x * blockDim.x + threadIdx.x;
    const int i = (int)(g >> 4);
    if (i >= nrows) return;
    const int c = ((int)g & 15) * 8;
    float own[8], acc[8] = {0.f, 0.f, 0.f, 0.f, 0.f, 0.f, 0.f, 0.f}, v[8];
    load8(h3t + (size_t)i * D + c, own);
    const int base = off[i], deg = cnt[i];
    for (int d = 0; d < deg; ++d) {
        const int eid = el[base + d];
        const int sib = src34[eid ^ 1];
        load8(h3t + (size_t)sib * D + c, v);
        #pragma unroll
        for (int j = 0; j < 8; ++j) acc[j] += v[j];
    }
    #pragma unroll
    for (int j = 0; j < 8; ++j) acc[j] *= own[j];
    store8(h3dn + (size_t)i * D + c, acc);
}

// ---- dst[i] = sum over CSR edges e of val[el[e]>>1] ----
template<typename TI, typename TO>
__global__ void gather_sum_kernel(const TI* __restrict__ val,
                                  const int* __restrict__ off, const int* __restrict__ cnt,
                                  const int* __restrict__ el,
                                  TO* __restrict__ dst, int nrows)
{
    const long long g = (long long)blockIdx.x * blockDim.x + threadIdx.x;
    const int i = (int)(g >> 4);
    if (i >= nrows) return;
    const int c = ((int)g & 15) * 8;
    float acc[8] = {0.f, 0.f, 0.f, 0.f, 0.f, 0.f, 0.f, 0.f}, v[8];
    const int base = off[i], deg = cnt[i];
    for (int d = 0; d < deg; ++d) {
        const int j = el[base + d] >> 1;
        load8(val + (size_t)j * D + c, v);
        #pragma unroll
        for (int jj = 0; jj < 8; ++jj) acc[jj] += v[jj];
    }
    store8(dst + (size_t)i * D + c, acc);
}

// diagnostic: if workspace too small, report its size via d_out[0]
__global__ void ws_report_kernel(float* out, float v) {
    if (threadIdx.x == 0 && blockIdx.x == 0) out[0] = v;
}

extern "C" void kernel_launch(void* const* d_in, const int* in_sizes, int n_in,
                              void* d_out, int out_size, void* d_ws, size_t ws_size,
                              hipStream_t stream)
{
    const float* feat = (const float*)d_in[0];
    const float* W1a = (const float*)d_in[1];  const float* b1a = (const float*)d_in[2];
    const float* W1b = (const float*)d_in[3];  const float* b1b = (const float*)d_in[4];
    const float* W2a = (const float*)d_in[5];  const float* b2a = (const float*)d_in[6];
    const float* W2b = (const float*)d_in[7];  const float* b2b = (const float*)d_in[8];
    const float* W3a = (const float*)d_in[9];  const float* b3a = (const float*)d_in[10];
    const float* W3b = (const float*)d_in[11]; const float* b3b = (const float*)d_in[12];
    const float* Wo  = (const float*)d_in[13]; const float* bo  = (const float*)d_in[14];
    const int* src12 = (const int*)d_in[15];
    const int* src23 = (const int*)d_in[17];
    const int* src34 = (const int*)d_in[19];

    const int N1 = in_sizes[0] / D;
    const int N2 = in_sizes[15] / 2;
    const int N3 = in_sizes[17] / 2;
    const int N4 = in_sizes[19] / 2;
    const int E12 = 2 * N2, E23 = 2 * N3, E34 = 2 * N4;

    // ---- workspace layout ----
    // f16: h1[N1], h2on1[N1], h2t[N2], regB[N3 f16] (h3t -> h2dn as f32: N2*4B == N3*2B)
    // f32: regC[N3] (h3dn -> hdown as f16)
    char* p = (char*)d_ws;
    f16* h1    = (f16*)p;  p += (size_t)N1 * D * sizeof(f16);
    f16* h2on1 = (f16*)p;  p += (size_t)N1 * D * sizeof(f16);
    f16* h2t   = (f16*)p;  p += (size_t)N2 * D * sizeof(f16);
    f16* h3t   = (f16*)p;  float* h2dn = (float*)h3t;   // alias: h3t dead after prod_gather
    p += (size_t)N3 * D * sizeof(f16);
    float* h3dn = (float*)p;  f16* hdown = (f16*)h3dn;  // alias: h3dn dead after h2dn gather
    p += (size_t)N3 * D * sizeof(float);

    int* cnt12 = (int*)p;
    int* off12 = cnt12 + N1; int* cur12 = off12 + N1; int* el12 = cur12 + N1;
    int* cnt23 = el12 + E12; int* off23 = cnt23 + N2; int* cur23 = off23 + N2; int* el23 = cur23 + N2;
    int* cnt34 = el23 + E23; int* off34 = cnt34 + N3; int* cur34 = off34 + N3; int* el34 = cur34 + N3;
    int* bsum  = el34 + E34;

    char* wraw = (char*)(bsum + 1024);
    wraw = (char*)(((uintptr_t)wraw + 31) & ~(uintptr_t)31);
    f16* WaT1 = (f16*)wraw;
    f16* WbT1 = WaT1 + D * D;
    f16* WaT2 = WbT1 + D * D;
    f16* WbT2 = WaT2 + D * D;
    f16* WaT3 = WbT2 + D * D;
    f16* WbT3 = WaT3 + D * D;
    f16* WoT  = WbT3 + D * D;   // [128][384]

    const size_t need = (char*)(WoT + 384 * D) - (char*)d_ws;
    if (ws_size < need) {
        ws_report_kernel<<<1, 64, 0, stream>>>((float*)d_out, (float)ws_size);
        return;
    }

    dim3 blk(256);
    auto tiles    = [](int n) { return dim3((unsigned)((n + 63) / 64)); };
    auto eblk     = [](int e) { return dim3((unsigned)((e + 255) / 256)); };
    auto rowblk16 = [](long long rows) { return dim3((unsigned)((rows * 16 + 255) / 256)); };

    // ---- weight convert (f16, transposed) ----
    wconv_kernel<<<dim3(64), blk, 0, stream>>>(W1a, WaT1, D, D);
    wconv_kernel<<<dim3(64), blk, 0, stream>>>(W1b, WbT1, D, D);
    wconv_kernel<<<dim3(64), blk, 0, stream>>>(W2a, WaT2, D, D);
    wconv_kernel<<<dim3(64), blk, 0, stream>>>(W2b, WbT2, D, D);
    wconv_kernel<<<dim3(64), blk, 0, stream>>>(W3a, WaT3, D, D);
    wconv_kernel<<<dim3(64), blk, 0, stream>>>(W3b, WbT3, D, D);
    wconv_kernel<<<dim3(192), blk, 0, stream>>>(Wo, WoT, 384, D);

    // ---- build reverse CSRs ----
    hipMemsetAsync(cnt12, 0, (size_t)N1 * sizeof(int), stream);
    hipMemsetAsync(cnt23, 0, (size_t)N2 * sizeof(int), stream);
    hipMemsetAsync(cnt34, 0, (size_t)N3 * sizeof(int), stream);
    hist_kernel<<<eblk(E12), blk, 0, stream>>>(src12, E12, cnt12);
    hist_kernel<<<eblk(E23), blk, 0, stream>>>(src23, E23, cnt23);
    hist_kernel<<<eblk(E34), blk, 0, stream>>>(src34, E34, cnt34);
    auto scan3 = [&](int* cnt, int* off, int* cur, int n) {
        const int nb = (n + SCAN_T - 1) / SCAN_T;
        scan_reduce_kernel<<<dim3((unsigned)nb), dim3(SCAN_T), 0, stream>>>(cnt, n, bsum);
        scan_top_kernel<<<1, 1024, 0, stream>>>(bsum, nb);
        scan_apply_kernel<<<dim3((unsigned)nb), dim3(SCAN_T), 0, stream>>>(cnt, n, bsum, off, cur);
    };
    scan3(cnt12, off12, cur12, N1);
    fill_kernel<<<eblk(E12), blk, 0, stream>>>(src12, E12, cur12, el12);
    scan3(cnt23, off23, cur23, N2);
    fill_kernel<<<eblk(E23), blk, 0, stream>>>(src23, E23, cur23, el23);
    scan3(cnt34, off34, cur34, N3);
    fill_kernel<<<eblk(E34), blk, 0, stream>>>(src34, E34, cur34, el34);

    // ---- upward (MFMA MLPs, f16 intermediates) ----
    mlp_mfma_kernel<false><<<tiles(N1), blk, 0, stream>>>(feat, nullptr, WaT1, b1a, WbT1, b1b, h1, N1);
    mlp_mfma_kernel<true ><<<tiles(N2), blk, 0, stream>>>(h1, src12, WaT2, b2a, WbT2, b2b, h2t, N2);
    gather_sum_kernel<f16, f16><<<rowblk16(N1), blk, 0, stream>>>(h2t, off12, cnt12, el12, h2on1, N1);
    mlp_mfma_kernel<true ><<<tiles(N3), blk, 0, stream>>>(h2t, src23, WaT3, b3a, WbT3, b3b, h3t, N3);

    // ---- downward (gathers; sum-chain kept fp32) ----
    prod_gather_kernel<<<rowblk16(N3), blk, 0, stream>>>(h3t, src34, off34, cnt34, el34, h3dn, N3);
    gather_sum_kernel<float, float><<<rowblk16(N2), blk, 0, stream>>>(h3dn, off23, cnt23, el23, h2dn, N2);
    gather_sum_kernel<float, f16 ><<<rowblk16(N1), blk, 0, stream>>>(h2dn, off12, cnt12, el12, hdown, N1);

    // ---- final fused concat-linear + SiLU (f32 out) ----
    out_mfma_kernel<<<tiles(N1), blk, 0, stream>>>(h1, h2on1, hdown, WoT, bo, (float*)d_out, N1);
}

// Round 6
// 408.742 us; speedup vs baseline: 7.9974x; 1.1837x over previous
//
#include <hip/hip_runtime.h>

#define D 128
#define SCAN_T 512
#define XSH 136   // f16 row stride (272 B = 16*17): 16B-aligned rows, spreads banks

typedef _Float16 f16;
typedef __attribute__((ext_vector_type(8))) _Float16 f16x8;
typedef __attribute__((ext_vector_type(4))) float    f32x4;

__device__ __forceinline__ float silu_f(float x) {
    return x / (1.0f + __expf(-x));
}

// ---------------- weight pre-convert: WT[n][k] = (f16) W[k][n] ----------------
__global__ void wconv_kernel(const float* __restrict__ W, f16* __restrict__ WT, int K, int N) {
    const int idx = blockIdx.x * blockDim.x + threadIdx.x;
    if (idx >= N * K) return;
    const int n = idx / K;
    const int k = idx - n * K;
    WT[idx] = (f16)W[(size_t)k * N + n];
}

// ---------------- MLP via MFMA: out = silu(in @ Wa + ba) @ Wb + bb ----------------
// Block = 256 thr = 4 waves; block owns 64 rows; wave w owns output cols [32w,32w+32).
// Weight fragments live in registers for the whole block (loaded once).
template<bool GATHER>
__launch_bounds__(256)
__global__ void mlp_mfma_kernel(const void* __restrict__ in_, const int* __restrict__ src,
                                const f16* __restrict__ WaT, const float* __restrict__ ba,
                                const f16* __restrict__ WbT, const float* __restrict__ bb,
                                f16* __restrict__ out, int nrows)
{
    __shared__ f16 xs[64][XSH];
    const int t = threadIdx.x;
    const int w = t >> 6, l = t & 63;
    const int cl = l & 15, kg = l >> 4;
    const int row0 = blockIdx.x * 64;

    // ---- weight fragments -> registers (once per block) ----
    f16x8 wa[2][4], wb[2][4];
    #pragma unroll
    for (int nt = 0; nt < 2; ++nt)
        #pragma unroll
        for (int kk = 0; kk < 4; ++kk) {
            const size_t o = (size_t)((w * 2 + nt) * 16 + cl) * D + kk * 32 + kg * 8;
            wa[nt][kk] = *(const f16x8*)(WaT + o);
            wb[nt][kk] = *(const f16x8*)(WbT + o);
        }

    // ---- stage A: 64 rows -> LDS (f16) ----
    {
        const int r = t >> 2, q = t & 3;
        const int g = row0 + r;
        f16* dst = &xs[r][q * 32];
        if (g < nrows) {
            if (GATHER) {
                const f16* in = (const f16*)in_;
                const int a = src[2 * g], b = src[2 * g + 1];
                const f16x8* pa = (const f16x8*)(in + (size_t)a * D + q * 32);
                const f16x8* pb = (const f16x8*)(in + (size_t)b * D + q * 32);
                #pragma unroll
                for (int i = 0; i < 4; ++i) {
                    f16x8 av = pa[i], bv = pb[i], hv;
                    #pragma unroll
                    for (int j = 0; j < 8; ++j) hv[j] = (f16)((float)av[j] * (float)bv[j]);
                    *(f16x8*)(dst + 8 * i) = hv;
                }
            } else {
                const float* in = (const float*)in_;
                const float4* p = (const float4*)(in + (size_t)g * D + q * 32);
                #pragma unroll
                for (int i = 0; i < 4; ++i) {
                    float4 v0 = p[2 * i], v1 = p[2 * i + 1];
                    f16x8 hv = {(f16)v0.x, (f16)v0.y, (f16)v0.z, (f16)v0.w,
                                (f16)v1.x, (f16)v1.y, (f16)v1.z, (f16)v1.w};
                    *(f16x8*)(dst + 8 * i) = hv;
                }
            }
        } else {
            f16x8 z = {};
            #pragma unroll
            for (int i = 0; i < 4; ++i) *(f16x8*)(dst + 8 * i) = z;
        }
    }
    __syncthreads();

    f32x4 acc[2][4];

    // ---- stage B: y = silu(x @ Wa + ba) ----
    #pragma unroll
    for (int nt = 0; nt < 2; ++nt)
        #pragma unroll
        for (int m = 0; m < 4; ++m) acc[nt][m] = (f32x4){0.f, 0.f, 0.f, 0.f};
    #pragma unroll
    for (int m = 0; m < 4; ++m)
        #pragma unroll
        for (int kk = 0; kk < 4; ++kk) {
            const f16x8 a = *(const f16x8*)&xs[m * 16 + cl][kk * 32 + kg * 8];
            acc[0][m] = __builtin_amdgcn_mfma_f32_16x16x32_f16(a, wa[0][kk], acc[0][m], 0, 0, 0);
            acc[1][m] = __builtin_amdgcn_mfma_f32_16x16x32_f16(a, wa[1][kk], acc[1][m], 0, 0, 0);
        }
    __syncthreads();
    // C/D layout (m89-verified): col = nt*16+cl, row = kg*4+r2.
    #pragma unroll
    for (int nt = 0; nt < 2; ++nt) {
        const float bv = ba[w * 32 + nt * 16 + cl];
        #pragma unroll
        for (int m = 0; m < 4; ++m)
            #pragma unroll
            for (int r2 = 0; r2 < 4; ++r2)
                xs[m * 16 + kg * 4 + r2][w * 32 + nt * 16 + cl] = (f16)silu_f(acc[nt][m][r2] + bv);
    }
    __syncthreads();

    // ---- stage C: z = y @ Wb + bb ----
    #pragma unroll
    for (int nt = 0; nt < 2; ++nt)
        #pragma unroll
        for (int m = 0; m < 4; ++m) acc[nt][m] = (f32x4){0.f, 0.f, 0.f, 0.f};
    #pragma unroll
    for (int m = 0; m < 4; ++m)
        #pragma unroll
        for (int kk = 0; kk < 4; ++kk) {
            const f16x8 a = *(const f16x8*)&xs[m * 16 + cl][kk * 32 + kg * 8];
            acc[0][m] = __builtin_amdgcn_mfma_f32_16x16x32_f16(a, wb[0][kk], acc[0][m], 0, 0, 0);
            acc[1][m] = __builtin_amdgcn_mfma_f32_16x16x32_f16(a, wb[1][kk], acc[1][m], 0, 0, 0);
        }
    __syncthreads();
    #pragma unroll
    for (int nt = 0; nt < 2; ++nt) {
        const float bv = bb[w * 32 + nt * 16 + cl];
        #pragma unroll
        for (int m = 0; m < 4; ++m)
            #pragma unroll
            for (int r2 = 0; r2 < 4; ++r2)
                xs[m * 16 + kg * 4 + r2][w * 32 + nt * 16 + cl] = (f16)(acc[nt][m][r2] + bv);
    }
    __syncthreads();

    // ---- coalesced f16 store ----
    {
        const int r = t >> 2, q = t & 3;
        const int g = row0 + r;
        if (g < nrows) {
            f16* dst = out + (size_t)g * D + q * 32;
            #pragma unroll
            for (int i = 0; i < 4; ++i)
                *(f16x8*)(dst + 8 * i) = *(const f16x8*)&xs[r][q * 32 + 8 * i];
        }
    }
}

// ---------------- final: out = silu(concat(h1,h2on1,hdown) @ Wo + bo), fp32 out ----------------
__launch_bounds__(256)
__global__ void out_mfma_kernel(const f16* __restrict__ h1, const f16* __restrict__ h2on1,
                                const f16* __restrict__ hdown,
                                const f16* __restrict__ WoT, const float* __restrict__ bo,
                                float* __restrict__ out, int nrows)
{
    __shared__ f16 xs[64][XSH];
    const int t = threadIdx.x;
    const int w = t >> 6, l = t & 63;
    const int cl = l & 15, kg = l >> 4;
    const int row0 = blockIdx.x * 64;

    f32x4 acc[2][4];
    #pragma unroll
    for (int nt = 0; nt < 2; ++nt)
        #pragma unroll
        for (int m = 0; m < 4; ++m) acc[nt][m] = (f32x4){0.f, 0.f, 0.f, 0.f};

    const f16* parts[3] = {h1, h2on1, hdown};
    #pragma unroll
    for (int p = 0; p < 3; ++p) {
        f16x8 wo[2][4];
        #pragma unroll
        for (int nt = 0; nt < 2; ++nt)
            #pragma unroll
            for (int kk = 0; kk < 4; ++kk)
                wo[nt][kk] = *(const f16x8*)(WoT + (size_t)((w * 2 + nt) * 16 + cl) * 384
                                             + p * D + kk * 32 + kg * 8);
        {
            const int r = t >> 2, q = t & 3;
            const int g = row0 + r;
            f16* dst = &xs[r][q * 32];
            if (g < nrows) {
                const f16x8* pp = (const f16x8*)(parts[p] + (size_t)g * D + q * 32);
                #pragma unroll
                for (int i = 0; i < 4; ++i) *(f16x8*)(dst + 8 * i) = pp[i];
            } else {
                f16x8 z = {};
                #pragma unroll
                for (int i = 0; i < 4; ++i) *(f16x8*)(dst + 8 * i) = z;
            }
        }
        __syncthreads();
        #pragma unroll
        for (int m = 0; m < 4; ++m)
            #pragma unroll
            for (int kk = 0; kk < 4; ++kk) {
                const f16x8 a = *(const f16x8*)&xs[m * 16 + cl][kk * 32 + kg * 8];
                acc[0][m] = __builtin_amdgcn_mfma_f32_16x16x32_f16(a, wo[0][kk], acc[0][m], 0, 0, 0);
                acc[1][m] = __builtin_amdgcn_mfma_f32_16x16x32_f16(a, wo[1][kk], acc[1][m], 0, 0, 0);
            }
        __syncthreads();
    }

    #pragma unroll
    for (int nt = 0; nt < 2; ++nt) {
        const float bv = bo[w * 32 + nt * 16 + cl];
        #pragma unroll
        for (int m = 0; m < 4; ++m)
            #pragma unroll
            for (int r2 = 0; r2 < 4; ++r2) {
                const int g = row0 + m * 16 + kg * 4 + r2;
                if (g < nrows) out[(size_t)g * D + w * 32 + nt * 16 + cl] = silu_f(acc[nt][m][r2] + bv);
            }
    }
}

// ---------------- fused CSR build over concatenated node space ----------------
// regions: n1 nodes at [0,N1), n2 at [N1,N1+N2), n3 at [N1+N2,NT)
__global__ void hist3_kernel(const int* __restrict__ s12, int E12,
                             const int* __restrict__ s23, int E23,
                             const int* __restrict__ s34, int E34,
                             int* __restrict__ cnt, int N1, int N2)
{
    const int g = blockIdx.x * blockDim.x + threadIdx.x;
    if (g < E12) {
        atomicAdd(&cnt[s12[g]], 1);
    } else if (g < E12 + E23) {
        atomicAdd(&cnt[N1 + s23[g - E12]], 1);
    } else if (g < E12 + E23 + E34) {
        atomicAdd(&cnt[N1 + N2 + s34[g - E12 - E23]], 1);
    }
}

__global__ void scan_reduce_kernel(const int* __restrict__ cnt, int n, int* __restrict__ bsum) {
    __shared__ int s[SCAN_T];
    const int t = threadIdx.x, b = blockIdx.x;
    const int i = b * SCAN_T + t;
    s[t] = (i < n) ? cnt[i] : 0;
    __syncthreads();
    for (int st = SCAN_T / 2; st > 0; st >>= 1) {
        if (t < st) s[t] += s[t + st];
        __syncthreads();
    }
    if (t == 0) bsum[b] = s[0];
}

__global__ void scan_top_kernel(int* __restrict__ bsum, int nb) {
    __shared__ int s[1024];
    const int t = threadIdx.x;
    int v = (t < nb) ? bsum[t] : 0;
    s[t] = v;
    __syncthreads();
    for (int off = 1; off < 1024; off <<= 1) {
        int u = (t >= off) ? s[t - off] : 0;
        __syncthreads();
        s[t] += u;
        __syncthreads();
    }
    if (t < nb) bsum[t] = s[t] - v;
}

__global__ void scan_apply_kernel(const int* __restrict__ cnt, int n,
                                  const int* __restrict__ bsum,
                                  int* __restrict__ off, int* __restrict__ cur) {
    __shared__ int s[SCAN_T];
    const int t = threadIdx.x, b = blockIdx.x;
    const int i = b * SCAN_T + t;
    const int v = (i < n) ? cnt[i] : 0;
    s[t] = v;
    __syncthreads();
    for (int o = 1; o < SCAN_T; o <<= 1) {
        int u = (t >= o) ? s[t - o] : 0;
        __syncthreads();
        s[t] += u;
        __syncthreads();
    }
    if (i < n) {
        const int ex = s[t] - v + bsum[b];
        off[i] = ex;
        cur[i] = ex;
    }
}

// fill with PRE-RESOLVED payloads:
//   e12 edge e -> payload e>>1 (n2 row index)
//   e23 edge e -> payload e>>1 (n3 row index)
//   e34 edge e -> payload src34[e^1] (sibling n3 row index)
__global__ void fill3_kernel(const int* __restrict__ s12, int E12,
                             const int* __restrict__ s23, int E23,
                             const int* __restrict__ s34, int E34,
                             int* __restrict__ cur, int* __restrict__ el,
                             int N1, int N2)
{
    const int g = blockIdx.x * blockDim.x + threadIdx.x;
    if (g < E12) {
        const int p = atomicAdd(&cur[s12[g]], 1);
        el[p] = g >> 1;
    } else if (g < E12 + E23) {
        const int e = g - E12;
        const int p = atomicAdd(&cur[N1 + s23[e]], 1);
        el[p] = e >> 1;
    } else if (g < E12 + E23 + E34) {
        const int e = g - E12 - E23;
        const int p = atomicAdd(&cur[N1 + N2 + s34[e]], 1);
        el[p] = s34[e ^ 1];
    }
}

// ---- h3dn[i] = h3t[i] * sum of h3t[sibling] (payload = sibling index), f16 out ----
__global__ void prod_gather_kernel(const f16* __restrict__ h3t,
                                   const int* __restrict__ off, const int* __restrict__ cnt,
                                   const int* __restrict__ el,
                                   f16* __restrict__ h3dn, int nrows)
{
    const long long g = (long long)blockIdx.x * blockDim.x + threadIdx.x;
    const int i = (int)(g >> 4);
    if (i >= nrows) return;
    const int c = ((int)g & 15) * 8;
    const f16x8 ownv = *(const f16x8*)(h3t + (size_t)i * D + c);
    float acc0[8] = {}, acc1[8] = {};
    const int base = off[i], deg = cnt[i];
    int d = 0;
    for (; d + 2 <= deg; d += 2) {
        const int s0 = el[base + d], s1 = el[base + d + 1];
        const f16x8 v0 = *(const f16x8*)(h3t + (size_t)s0 * D + c);
        const f16x8 v1 = *(const f16x8*)(h3t + (size_t)s1 * D + c);
        #pragma unroll
        for (int j = 0; j < 8; ++j) { acc0[j] += (float)v0[j]; acc1[j] += (float)v1[j]; }
    }
    if (d < deg) {
        const int s0 = el[base + d];
        const f16x8 v0 = *(const f16x8*)(h3t + (size_t)s0 * D + c);
        #pragma unroll
        for (int j = 0; j < 8; ++j) acc0[j] += (float)v0[j];
    }
    f16x8 r;
    #pragma unroll
    for (int j = 0; j < 8; ++j) r[j] = (f16)((acc0[j] + acc1[j]) * (float)ownv[j]);
    *(f16x8*)(h3dn + (size_t)i * D + c) = r;
}

// ---- dst[i] = sum of val[payload] over CSR entries (f16 in/out, fp32 accum) ----
__global__ void gather_sum_kernel(const f16* __restrict__ val,
                                  const int* __restrict__ off, const int* __restrict__ cnt,
                                  const int* __restrict__ el,
                                  f16* __restrict__ dst, int nrows)
{
    const long long g = (long long)blockIdx.x * blockDim.x + threadIdx.x;
    const int i = (int)(g >> 4);
    if (i >= nrows) return;
    const int c = ((int)g & 15) * 8;
    float acc0[8] = {}, acc1[8] = {};
    const int base = off[i], deg = cnt[i];
    int d = 0;
    for (; d + 2 <= deg; d += 2) {
        const int s0 = el[base + d], s1 = el[base + d + 1];
        const f16x8 v0 = *(const f16x8*)(val + (size_t)s0 * D + c);
        const f16x8 v1 = *(const f16x8*)(val + (size_t)s1 * D + c);
        #pragma unroll
        for (int j = 0; j < 8; ++j) { acc0[j] += (float)v0[j]; acc1[j] += (float)v1[j]; }
    }
    if (d < deg) {
        const int s0 = el[base + d];
        const f16x8 v0 = *(const f16x8*)(val + (size_t)s0 * D + c);
        #pragma unroll
        for (int j = 0; j < 8; ++j) acc0[j] += (float)v0[j];
    }
    f16x8 r;
    #pragma unroll
    for (int j = 0; j < 8; ++j) r[j] = (f16)(acc0[j] + acc1[j]);
    *(f16x8*)(dst + (size_t)i * D + c) = r;
}

// diagnostic: if workspace too small, report its size via d_out[0]
__global__ void ws_report_kernel(float* out, float v) {
    if (threadIdx.x == 0 && blockIdx.x == 0) out[0] = v;
}

extern "C" void kernel_launch(void* const* d_in, const int* in_sizes, int n_in,
                              void* d_out, int out_size, void* d_ws, size_t ws_size,
                              hipStream_t stream)
{
    const float* feat = (const float*)d_in[0];
    const float* W1a = (const float*)d_in[1];  const float* b1a = (const float*)d_in[2];
    const float* W1b = (const float*)d_in[3];  const float* b1b = (const float*)d_in[4];
    const float* W2a = (const float*)d_in[5];  const float* b2a = (const float*)d_in[6];
    const float* W2b = (const float*)d_in[7];  const float* b2b = (const float*)d_in[8];
    const float* W3a = (const float*)d_in[9];  const float* b3a = (const float*)d_in[10];
    const float* W3b = (const float*)d_in[11]; const float* b3b = (const float*)d_in[12];
    const float* Wo  = (const float*)d_in[13]; const float* bo  = (const float*)d_in[14];
    const int* src12 = (const int*)d_in[15];
    const int* src23 = (const int*)d_in[17];
    const int* src34 = (const int*)d_in[19];

    const int N1 = in_sizes[0] / D;
    const int N2 = in_sizes[15] / 2;
    const int N3 = in_sizes[17] / 2;
    const int N4 = in_sizes[19] / 2;
    const int E12 = 2 * N2, E23 = 2 * N3, E34 = 2 * N4;
    const int NT = N1 + N2 + N3;
    const int Etot = E12 + E23 + E34;

    // ---- workspace layout (all f16 features) ----
    char* p = (char*)d_ws;
    f16* h1    = (f16*)p;  p += (size_t)N1 * D * sizeof(f16);
    f16* h2on1 = (f16*)p;  p += (size_t)N1 * D * sizeof(f16);
    f16* h2t   = (f16*)p;  p += (size_t)N2 * D * sizeof(f16);
    f16* h3t   = (f16*)p;  f16* h2dn  = h3t;    // alias: h3t dead after prod_gather
    p += (size_t)N3 * D * sizeof(f16);
    f16* h3dn  = (f16*)p;  f16* hdown = h3dn;   // alias: h3dn dead after h2dn gather
    p += (size_t)N3 * D * sizeof(f16);

    int* cnt = (int*)p;
    int* off = cnt + NT;
    int* cur = off + NT;
    int* el  = cur + NT;
    int* bsum = el + Etot;

    char* wraw = (char*)(bsum + 1024);
    wraw = (char*)(((uintptr_t)wraw + 31) & ~(uintptr_t)31);
    f16* WaT1 = (f16*)wraw;
    f16* WbT1 = WaT1 + D * D;
    f16* WaT2 = WbT1 + D * D;
    f16* WbT2 = WaT2 + D * D;
    f16* WaT3 = WbT2 + D * D;
    f16* WbT3 = WaT3 + D * D;
    f16* WoT  = WbT3 + D * D;   // [128][384]

    const size_t need = (char*)(WoT + 384 * D) - (char*)d_ws;
    if (ws_size < need) {
        ws_report_kernel<<<1, 64, 0, stream>>>((float*)d_out, (float)ws_size);
        return;
    }

    dim3 blk(256);
    auto tiles    = [](int n) { return dim3((unsigned)((n + 63) / 64)); };
    auto eblk     = [](int e) { return dim3((unsigned)((e + 255) / 256)); };
    auto rowblk16 = [](long long rows) { return dim3((unsigned)((rows * 16 + 255) / 256)); };

    // ---- weight convert (f16, transposed) ----
    wconv_kernel<<<dim3(64), blk, 0, stream>>>(W1a, WaT1, D, D);
    wconv_kernel<<<dim3(64), blk, 0, stream>>>(W1b, WbT1, D, D);
    wconv_kernel<<<dim3(64), blk, 0, stream>>>(W2a, WaT2, D, D);
    wconv_kernel<<<dim3(64), blk, 0, stream>>>(W2b, WbT2, D, D);
    wconv_kernel<<<dim3(64), blk, 0, stream>>>(W3a, WaT3, D, D);
    wconv_kernel<<<dim3(64), blk, 0, stream>>>(W3b, WbT3, D, D);
    wconv_kernel<<<dim3(192), blk, 0, stream>>>(Wo, WoT, 384, D);

    // ---- fused CSR build (one hist, one scan, one fill) ----
    hipMemsetAsync(cnt, 0, (size_t)NT * sizeof(int), stream);
    hist3_kernel<<<eblk(Etot), blk, 0, stream>>>(src12, E12, src23, E23, src34, E34, cnt, N1, N2);
    {
        const int nb = (NT + SCAN_T - 1) / SCAN_T;   // 684 <= 1024
        scan_reduce_kernel<<<dim3((unsigned)nb), dim3(SCAN_T), 0, stream>>>(cnt, NT, bsum);
        scan_top_kernel<<<1, 1024, 0, stream>>>(bsum, nb);
        scan_apply_kernel<<<dim3((unsigned)nb), dim3(SCAN_T), 0, stream>>>(cnt, NT, bsum, off, cur);
    }
    fill3_kernel<<<eblk(Etot), blk, 0, stream>>>(src12, E12, src23, E23, src34, E34, cur, el, N1, N2);

    // ---- upward (MFMA MLPs, f16 intermediates) ----
    mlp_mfma_kernel<false><<<tiles(N1), blk, 0, stream>>>(feat, nullptr, WaT1, b1a, WbT1, b1b, h1, N1);
    mlp_mfma_kernel<true ><<<tiles(N2), blk, 0, stream>>>(h1, src12, WaT2, b2a, WbT2, b2b, h2t, N2);
    gather_sum_kernel<<<rowblk16(N1), blk, 0, stream>>>(h2t, off, cnt, el, h2on1, N1);
    mlp_mfma_kernel<true ><<<tiles(N3), blk, 0, stream>>>(h2t, src23, WaT3, b3a, WbT3, b3b, h3t, N3);

    // ---- downward (all f16, fp32 accum; pre-resolved payloads) ----
    prod_gather_kernel<<<rowblk16(N3), blk, 0, stream>>>(h3t, off + N1 + N2, cnt + N1 + N2, el, h3dn, N3);
    gather_sum_kernel<<<rowblk16(N2), blk, 0, stream>>>(h3dn, off + N1, cnt + N1, el, h2dn, N2);
    gather_sum_kernel<<<rowblk16(N1), blk, 0, stream>>>(h2dn, off, cnt, el, hdown, N1);

    // ---- final fused concat-linear + SiLU (f32 out) ----
    out_mfma_kernel<<<tiles(N1), blk, 0, stream>>>(h1, h2on1, hdown, WoT, bo, (float*)d_out, N1);
}

// Round 7
// 288.540 us; speedup vs baseline: 11.3290x; 1.4166x over previous
//
#include <hip/hip_runtime.h>

#define D 128
#define XSH 136   // f16 row stride (272 B = 16*17): 16B-aligned rows, spreads banks

#define SHIFT 11
#define NPB   2048            // nodes per bucket = 1 << SHIFT
#define EPT   8               // edges per thread in csr pass 1

typedef _Float16 f16;
typedef __attribute__((ext_vector_type(8))) _Float16 f16x8;
typedef __attribute__((ext_vector_type(4))) float    f32x4;

__device__ __forceinline__ float silu_f(float x) {
    return x / (1.0f + __expf(-x));
}

// ---------------- weight pre-convert (all 7 weights in one launch) ----------------
// Layout in WT (f16, consecutive): WaT1,WbT1,WaT2,WbT2,WaT3,WbT3 (each [128][128] as [n][k]),
// then WoT [128][384] as [n][k]. Square weights: blocks 0..383 (64 per weight); Wo: 384..575.
struct WPtrs { const float* s0; const float* s1; const float* s2;
               const float* s3; const float* s4; const float* s5; };
__global__ void wconv_all_kernel(WPtrs wp, const float* __restrict__ Wo, f16* __restrict__ WT)
{
    const int blk = blockIdx.x, t = threadIdx.x;
    if (blk < 384) {
        const int wid = blk >> 6;
        const int off = ((blk & 63) << 8) + t;     // 0..16383
        const int n = off >> 7, k = off & 127;
        const float* s;
        switch (wid) {
            case 0: s = wp.s0; break;
            case 1: s = wp.s1; break;
            case 2: s = wp.s2; break;
            case 3: s = wp.s3; break;
            case 4: s = wp.s4; break;
            default: s = wp.s5; break;
        }
        WT[(wid << 14) + off] = (f16)s[(k << 7) + n];
    } else {
        const int off = ((blk - 384) << 8) + t;    // 0..49151 = n*384+k
        const int n = off / 384, k = off - n * 384;
        WT[(6 << 14) + off] = (f16)Wo[k * 128 + n];
    }
}

// ---------------- MLP via MFMA: out = silu(in @ Wa + ba) @ Wb + bb ----------------
template<bool GATHER>
__launch_bounds__(256)
__global__ void mlp_mfma_kernel(const void* __restrict__ in_, const int* __restrict__ src,
                                const f16* __restrict__ WaT, const float* __restrict__ ba,
                                const f16* __restrict__ WbT, const float* __restrict__ bb,
                                f16* __restrict__ out, int nrows)
{
    __shared__ f16 xs[64][XSH];
    const int t = threadIdx.x;
    const int w = t >> 6, l = t & 63;
    const int cl = l & 15, kg = l >> 4;
    const int row0 = blockIdx.x * 64;

    f16x8 wa[2][4], wb[2][4];
    #pragma unroll
    for (int nt = 0; nt < 2; ++nt)
        #pragma unroll
        for (int kk = 0; kk < 4; ++kk) {
            const size_t o = (size_t)((w * 2 + nt) * 16 + cl) * D + kk * 32 + kg * 8;
            wa[nt][kk] = *(const f16x8*)(WaT + o);
            wb[nt][kk] = *(const f16x8*)(WbT + o);
        }

    {
        const int r = t >> 2, q = t & 3;
        const int g = row0 + r;
        f16* dst = &xs[r][q * 32];
        if (g < nrows) {
            if (GATHER) {
                const f16* in = (const f16*)in_;
                const int a = src[2 * g], b = src[2 * g + 1];
                const f16x8* pa = (const f16x8*)(in + (size_t)a * D + q * 32);
                const f16x8* pb = (const f16x8*)(in + (size_t)b * D + q * 32);
                #pragma unroll
                for (int i = 0; i < 4; ++i) {
                    f16x8 av = pa[i], bv = pb[i], hv;
                    #pragma unroll
                    for (int j = 0; j < 8; ++j) hv[j] = (f16)((float)av[j] * (float)bv[j]);
                    *(f16x8*)(dst + 8 * i) = hv;
                }
            } else {
                const float* in = (const float*)in_;
                const float4* p = (const float4*)(in + (size_t)g * D + q * 32);
                #pragma unroll
                for (int i = 0; i < 4; ++i) {
                    float4 v0 = p[2 * i], v1 = p[2 * i + 1];
                    f16x8 hv = {(f16)v0.x, (f16)v0.y, (f16)v0.z, (f16)v0.w,
                                (f16)v1.x, (f16)v1.y, (f16)v1.z, (f16)v1.w};
                    *(f16x8*)(dst + 8 * i) = hv;
                }
            }
        } else {
            f16x8 z = {};
            #pragma unroll
            for (int i = 0; i < 4; ++i) *(f16x8*)(dst + 8 * i) = z;
        }
    }
    __syncthreads();

    f32x4 acc[2][4];

    #pragma unroll
    for (int nt = 0; nt < 2; ++nt)
        #pragma unroll
        for (int m = 0; m < 4; ++m) acc[nt][m] = (f32x4){0.f, 0.f, 0.f, 0.f};
    #pragma unroll
    for (int m = 0; m < 4; ++m)
        #pragma unroll
        for (int kk = 0; kk < 4; ++kk) {
            const f16x8 a = *(const f16x8*)&xs[m * 16 + cl][kk * 32 + kg * 8];
            acc[0][m] = __builtin_amdgcn_mfma_f32_16x16x32_f16(a, wa[0][kk], acc[0][m], 0, 0, 0);
            acc[1][m] = __builtin_amdgcn_mfma_f32_16x16x32_f16(a, wa[1][kk], acc[1][m], 0, 0, 0);
        }
    __syncthreads();
    // C/D layout (m89-verified): col = nt*16+cl, row = kg*4+r2.
    #pragma unroll
    for (int nt = 0; nt < 2; ++nt) {
        const float bv = ba[w * 32 + nt * 16 + cl];
        #pragma unroll
        for (int m = 0; m < 4; ++m)
            #pragma unroll
            for (int r2 = 0; r2 < 4; ++r2)
                xs[m * 16 + kg * 4 + r2][w * 32 + nt * 16 + cl] = (f16)silu_f(acc[nt][m][r2] + bv);
    }
    __syncthreads();

    #pragma unroll
    for (int nt = 0; nt < 2; ++nt)
        #pragma unroll
        for (int m = 0; m < 4; ++m) acc[nt][m] = (f32x4){0.f, 0.f, 0.f, 0.f};
    #pragma unroll
    for (int m = 0; m < 4; ++m)
        #pragma unroll
        for (int kk = 0; kk < 4; ++kk) {
            const f16x8 a = *(const f16x8*)&xs[m * 16 + cl][kk * 32 + kg * 8];
            acc[0][m] = __builtin_amdgcn_mfma_f32_16x16x32_f16(a, wb[0][kk], acc[0][m], 0, 0, 0);
            acc[1][m] = __builtin_amdgcn_mfma_f32_16x16x32_f16(a, wb[1][kk], acc[1][m], 0, 0, 0);
        }
    __syncthreads();
    #pragma unroll
    for (int nt = 0; nt < 2; ++nt) {
        const float bv = bb[w * 32 + nt * 16 + cl];
        #pragma unroll
        for (int m = 0; m < 4; ++m)
            #pragma unroll
            for (int r2 = 0; r2 < 4; ++r2)
                xs[m * 16 + kg * 4 + r2][w * 32 + nt * 16 + cl] = (f16)(acc[nt][m][r2] + bv);
    }
    __syncthreads();

    {
        const int r = t >> 2, q = t & 3;
        const int g = row0 + r;
        if (g < nrows) {
            f16* dst = out + (size_t)g * D + q * 32;
            #pragma unroll
            for (int i = 0; i < 4; ++i)
                *(f16x8*)(dst + 8 * i) = *(const f16x8*)&xs[r][q * 32 + 8 * i];
        }
    }
}

// ---------------- final: out = silu(concat(h1,h2on1,hdown) @ Wo + bo), fp32 out ----------------
__launch_bounds__(256)
__global__ void out_mfma_kernel(const f16* __restrict__ h1, const f16* __restrict__ h2on1,
                                const f16* __restrict__ hdown,
                                const f16* __restrict__ WoT, const float* __restrict__ bo,
                                float* __restrict__ out, int nrows)
{
    __shared__ f16 xs[64][XSH];
    const int t = threadIdx.x;
    const int w = t >> 6, l = t & 63;
    const int cl = l & 15, kg = l >> 4;
    const int row0 = blockIdx.x * 64;

    f32x4 acc[2][4];
    #pragma unroll
    for (int nt = 0; nt < 2; ++nt)
        #pragma unroll
        for (int m = 0; m < 4; ++m) acc[nt][m] = (f32x4){0.f, 0.f, 0.f, 0.f};

    const f16* parts[3] = {h1, h2on1, hdown};
    #pragma unroll
    for (int p = 0; p < 3; ++p) {
        f16x8 wo[2][4];
        #pragma unroll
        for (int nt = 0; nt < 2; ++nt)
            #pragma unroll
            for (int kk = 0; kk < 4; ++kk)
                wo[nt][kk] = *(const f16x8*)(WoT + (size_t)((w * 2 + nt) * 16 + cl) * 384
                                             + p * D + kk * 32 + kg * 8);
        {
            const int r = t >> 2, q = t & 3;
            const int g = row0 + r;
            f16* dst = &xs[r][q * 32];
            if (g < nrows) {
                const f16x8* pp = (const f16x8*)(parts[p] + (size_t)g * D + q * 32);
                #pragma unroll
                for (int i = 0; i < 4; ++i) *(f16x8*)(dst + 8 * i) = pp[i];
            } else {
                f16x8 z = {};
                #pragma unroll
                for (int i = 0; i < 4; ++i) *(f16x8*)(dst + 8 * i) = z;
            }
        }
        __syncthreads();
        #pragma unroll
        for (int m = 0; m < 4; ++m)
            #pragma unroll
            for (int kk = 0; kk < 4; ++kk) {
                const f16x8 a = *(const f16x8*)&xs[m * 16 + cl][kk * 32 + kg * 8];
                acc[0][m] = __builtin_amdgcn_mfma_f32_16x16x32_f16(a, wo[0][kk], acc[0][m], 0, 0, 0);
                acc[1][m] = __builtin_amdgcn_mfma_f32_16x16x32_f16(a, wo[1][kk], acc[1][m], 0, 0, 0);
            }
        __syncthreads();
    }

    #pragma unroll
    for (int nt = 0; nt < 2; ++nt) {
        const float bv = bo[w * 32 + nt * 16 + cl];
        #pragma unroll
        for (int m = 0; m < 4; ++m)
            #pragma unroll
            for (int r2 = 0; r2 < 4; ++r2) {
                const int g = row0 + m * 16 + kg * 4 + r2;
                if (g < nrows) out[(size_t)g * D + w * 32 + nt * 16 + cl] = silu_f(acc[nt][m][r2] + bv);
            }
    }
}

// ================= bucketed reverse-CSR build =================
// node space: n1 at [0,N1), n2 at [N1,N1+N2), n3 at [N1+N2,NT). buckets of NPB nodes.
// payloads: e12 -> e>>1 (n2 idx), e23 -> e>>1 (n3 idx), e34 -> src34[e^1] (sibling n3 idx).

// pass 0: per-bucket edge histogram (LDS-staged)
__global__ void bucket_hist_kernel(const int* __restrict__ s12, int E12,
                                   const int* __restrict__ s23, int E23,
                                   const int* __restrict__ s34, int E34,
                                   int* __restrict__ bcnt, int N1, int N2, int nbkt)
{
    __shared__ int h[256];
    const int t = threadIdx.x;
    for (int i = t; i < 256; i += blockDim.x) h[i] = 0;
    __syncthreads();
    const int Etot = E12 + E23 + E34;
    for (int g = blockIdx.x * blockDim.x + t; g < Etot; g += gridDim.x * blockDim.x) {
        int node;
        if (g < E12) node = s12[g];
        else if (g < E12 + E23) node = N1 + s23[g - E12];
        else node = N1 + N2 + s34[g - E12 - E23];
        atomicAdd(&h[node >> SHIFT], 1);
    }
    __syncthreads();
    for (int i = t; i < nbkt; i += blockDim.x)
        if (h[i]) atomicAdd(&bcnt[i], h[i]);
}

// scan bucket counts (single block); bbase exclusive, sentinel, cursors
__global__ void bucket_scan_kernel(const int* __restrict__ bcnt, int* __restrict__ bbase,
                                   int* __restrict__ bcur, int nbkt, int Etot)
{
    __shared__ int s[256];
    const int t = threadIdx.x;
    const int v = (t < nbkt) ? bcnt[t] : 0;
    s[t] = v;
    __syncthreads();
    for (int d = 1; d < 256; d <<= 1) {
        const int u = (t >= d) ? s[t - d] : 0;
        __syncthreads();
        s[t] += u;
        __syncthreads();
    }
    if (t < nbkt) { const int ex = s[t] - v; bbase[t] = ex; bcur[t] = ex; }
    if (t == 0) bbase[nbkt] = Etot;
}

// pass 1: scatter (node,payload) records into bucket-segmented storage (coalesced-ish runs)
__global__ void csr_pass1_kernel(const int* __restrict__ s12, int E12,
                                 const int* __restrict__ s23, int E23,
                                 const int* __restrict__ s34, int E34,
                                 int* __restrict__ bcur, int2* __restrict__ recs,
                                 int N1, int N2, int nbkt)
{
    __shared__ int cnt[256];
    __shared__ int gbase[256];
    const int t = threadIdx.x;
    const int chunk = blockIdx.x * (256 * EPT);
    const int Etot = E12 + E23 + E34;
    for (int i = t; i < 256; i += 256) cnt[i] = 0;
    __syncthreads();
    int node_[EPT], pay_[EPT], br_[EPT];
    #pragma unroll
    for (int i = 0; i < EPT; ++i) {
        const int g = chunk + i * 256 + t;
        int node = -1, pay = 0, b = 0, r = 0;
        if (g < Etot) {
            if (g < E12) { node = s12[g]; pay = g >> 1; }
            else if (g < E12 + E23) { const int e = g - E12; node = N1 + s23[e]; pay = e >> 1; }
            else { const int e = g - E12 - E23; node = N1 + N2 + s34[e]; pay = s34[e ^ 1]; }
            b = node >> SHIFT;
            r = atomicAdd(&cnt[b], 1);
        }
        node_[i] = node; pay_[i] = pay; br_[i] = (b << 16) | r;   // r < 2048 fits
    }
    __syncthreads();
    if (t < nbkt && cnt[t]) gbase[t] = atomicAdd(&bcur[t], cnt[t]);
    __syncthreads();
    #pragma unroll
    for (int i = 0; i < EPT; ++i) {
        if (node_[i] >= 0) {
            const int b = br_[i] >> 16, r = br_[i] & 0xffff;
            recs[gbase[b] + r] = make_int2(node_[i], pay_[i]);
        }
    }
}

// pass 2: one block per bucket — local hist, block scan, write offcnt + el (L2-local)
__launch_bounds__(1024)
__global__ void csr_pass2_kernel(const int2* __restrict__ recs,
                                 const int* __restrict__ bbase,
                                 int2* __restrict__ offcnt, int* __restrict__ el, int NT)
{
    __shared__ int cnt2[NPB];
    __shared__ int pref[NPB];
    __shared__ int s1[NPB / 2];
    const int b = blockIdx.x, t = threadIdx.x;     // blockDim = 1024 = NPB/2
    const int node0 = b << SHIFT;
    const int k0 = bbase[b], k1 = bbase[b + 1];
    for (int i = t; i < NPB; i += 1024) cnt2[i] = 0;
    __syncthreads();
    for (int k = k0 + t; k < k1; k += 1024)
        atomicAdd(&cnt2[recs[k].x - node0], 1);
    __syncthreads();
    s1[t] = cnt2[2 * t] + cnt2[2 * t + 1];
    __syncthreads();
    for (int d = 1; d < 1024; d <<= 1) {
        const int u = (t >= d) ? s1[t - d] : 0;
        __syncthreads();
        s1[t] += u;
        __syncthreads();
    }
    {
        const int a = cnt2[2 * t];
        const int pairsum = a + cnt2[2 * t + 1];
        const int ex0 = s1[t] - pairsum;
        pref[2 * t] = ex0;
        pref[2 * t + 1] = ex0 + a;
    }
    __syncthreads();
    for (int i = t; i < NPB; i += 1024) {
        const int node = node0 + i;
        if (node < NT) offcnt[node] = make_int2(k0 + pref[i], cnt2[i]);
    }
    __syncthreads();
    for (int k = k0 + t; k < k1; k += 1024) {
        const int2 r = recs[k];
        const int pos = atomicAdd(&pref[r.x - node0], 1);
        el[k0 + pos] = r.y;
    }
}

// ---- h3dn[i] = h3t[i] * sum of h3t[sibling] (payload = sibling index), f16 out ----
__global__ void prod_gather_kernel(const f16* __restrict__ h3t,
                                   const int2* __restrict__ offcnt,
                                   const int* __restrict__ el,
                                   f16* __restrict__ h3dn, int nrows)
{
    const long long g = (long long)blockIdx.x * blockDim.x + threadIdx.x;
    const int i = (int)(g >> 4);
    if (i >= nrows) return;
    const int c = ((int)g & 15) * 8;
    const f16x8 ownv = *(const f16x8*)(h3t + (size_t)i * D + c);
    float acc0[8] = {}, acc1[8] = {};
    const int2 oc = offcnt[i];
    const int base = oc.x, deg = oc.y;
    int d = 0;
    for (; d + 2 <= deg; d += 2) {
        const int s0 = el[base + d], s1v = el[base + d + 1];
        const f16x8 v0 = *(const f16x8*)(h3t + (size_t)s0 * D + c);
        const f16x8 v1 = *(const f16x8*)(h3t + (size_t)s1v * D + c);
        #pragma unroll
        for (int j = 0; j < 8; ++j) { acc0[j] += (float)v0[j]; acc1[j] += (float)v1[j]; }
    }
    if (d < deg) {
        const int s0 = el[base + d];
        const f16x8 v0 = *(const f16x8*)(h3t + (size_t)s0 * D + c);
        #pragma unroll
        for (int j = 0; j < 8; ++j) acc0[j] += (float)v0[j];
    }
    f16x8 r;
    #pragma unroll
    for (int j = 0; j < 8; ++j) r[j] = (f16)((acc0[j] + acc1[j]) * (float)ownv[j]);
    *(f16x8*)(h3dn + (size_t)i * D + c) = r;
}

// ---- dst[i] = sum of val[payload] over CSR entries (f16 in/out, fp32 accum) ----
__global__ void gather_sum_kernel(const f16* __restrict__ val,
                                  const int2* __restrict__ offcnt,
                                  const int* __restrict__ el,
                                  f16* __restrict__ dst, int nrows)
{
    const long long g = (long long)blockIdx.x * blockDim.x + threadIdx.x;
    const int i = (int)(g >> 4);
    if (i >= nrows) return;
    const int c = ((int)g & 15) * 8;
    float acc0[8] = {}, acc1[8] = {};
    const int2 oc = offcnt[i];
    const int base = oc.x, deg = oc.y;
    int d = 0;
    for (; d + 2 <= deg; d += 2) {
        const int s0 = el[base + d], s1v = el[base + d + 1];
        const f16x8 v0 = *(const f16x8*)(val + (size_t)s0 * D + c);
        const f16x8 v1 = *(const f16x8*)(val + (size_t)s1v * D + c);
        #pragma unroll
        for (int j = 0; j < 8; ++j) { acc0[j] += (float)v0[j]; acc1[j] += (float)v1[j]; }
    }
    if (d < deg) {
        const int s0 = el[base + d];
        const f16x8 v0 = *(const f16x8*)(val + (size_t)s0 * D + c);
        #pragma unroll
        for (int j = 0; j < 8; ++j) acc0[j] += (float)v0[j];
    }
    f16x8 r;
    #pragma unroll
    for (int j = 0; j < 8; ++j) r[j] = (f16)(acc0[j] + acc1[j]);
    *(f16x8*)(dst + (size_t)i * D + c) = r;
}

// diagnostic: if workspace too small, report its size via d_out[0]
__global__ void ws_report_kernel(float* out, float v) {
    if (threadIdx.x == 0 && blockIdx.x == 0) out[0] = v;
}

extern "C" void kernel_launch(void* const* d_in, const int* in_sizes, int n_in,
                              void* d_out, int out_size, void* d_ws, size_t ws_size,
                              hipStream_t stream)
{
    const float* feat = (const float*)d_in[0];
    const float* W1a = (const float*)d_in[1];  const float* b1a = (const float*)d_in[2];
    const float* W1b = (const float*)d_in[3];  const float* b1b = (const float*)d_in[4];
    const float* W2a = (const float*)d_in[5];  const float* b2a = (const float*)d_in[6];
    const float* W2b = (const float*)d_in[7];  const float* b2b = (const float*)d_in[8];
    const float* W3a = (const float*)d_in[9];  const float* b3a = (const float*)d_in[10];
    const float* W3b = (const float*)d_in[11]; const float* b3b = (const float*)d_in[12];
    const float* Wo  = (const float*)d_in[13]; const float* bo  = (const float*)d_in[14];
    const int* src12 = (const int*)d_in[15];
    const int* src23 = (const int*)d_in[17];
    const int* src34 = (const int*)d_in[19];

    const int N1 = in_sizes[0] / D;
    const int N2 = in_sizes[15] / 2;
    const int N3 = in_sizes[17] / 2;
    const int N4 = in_sizes[19] / 2;
    const int E12 = 2 * N2, E23 = 2 * N3, E34 = 2 * N4;
    const int NT = N1 + N2 + N3;
    const int Etot = E12 + E23 + E34;
    const int NBKT = (NT + NPB - 1) >> SHIFT;

    // ---- workspace layout ----
    char* p = (char*)d_ws;
    f16* h1    = (f16*)p;  p += (size_t)N1 * D * sizeof(f16);
    f16* h2on1 = (f16*)p;  p += (size_t)N1 * D * sizeof(f16);
    f16* h2t   = (f16*)p;  p += (size_t)N2 * D * sizeof(f16);
    f16* h3t   = (f16*)p;  f16* h2dn  = h3t;    // alias: h3t dead after prod_gather
    p += (size_t)N3 * D * sizeof(f16);
    f16* h3dn  = (f16*)p;  f16* hdown = h3dn;   // alias: h3dn dead after h2dn gather
    p += (size_t)N3 * D * sizeof(f16);

    p = (char*)(((uintptr_t)p + 15) & ~(uintptr_t)15);
    int2* offcnt = (int2*)p;             p += (size_t)NT * sizeof(int2);
    int2* recs   = (int2*)p;             p += (size_t)Etot * sizeof(int2);
    int*  el     = (int*)p;              p += (size_t)Etot * sizeof(int);
    int*  bcnt   = (int*)p;              p += 256 * sizeof(int);
    int*  bbase  = (int*)p;              p += 257 * sizeof(int);
    int*  bcur   = (int*)p;              p += 256 * sizeof(int);

    p = (char*)(((uintptr_t)p + 31) & ~(uintptr_t)31);
    f16* WT = (f16*)p;                   // 6*16384 + 49152 f16
    f16* WaT1 = WT;
    f16* WbT1 = WaT1 + D * D;
    f16* WaT2 = WbT1 + D * D;
    f16* WbT2 = WaT2 + D * D;
    f16* WaT3 = WbT2 + D * D;
    f16* WbT3 = WaT3 + D * D;
    f16* WoT  = WbT3 + D * D;
    p = (char*)(WoT + 384 * D);

    const size_t need = p - (char*)d_ws;
    if (ws_size < need || NBKT > 256) {
        ws_report_kernel<<<1, 64, 0, stream>>>((float*)d_out, (float)ws_size);
        return;
    }

    dim3 blk(256);
    auto tiles    = [](int n) { return dim3((unsigned)((n + 63) / 64)); };
    auto rowblk16 = [](long long rows) { return dim3((unsigned)((rows * 16 + 255) / 256)); };

    // ---- weight convert: one launch ----
    WPtrs wp = {W1a, W1b, W2a, W2b, W3a, W3b};
    wconv_all_kernel<<<dim3(576), blk, 0, stream>>>(wp, Wo, WT);

    // ---- bucketed CSR build ----
    hipMemsetAsync(bcnt, 0, 256 * sizeof(int), stream);
    {
        const int nblk = (Etot + 2047) / 2048;
        bucket_hist_kernel<<<dim3((unsigned)nblk), blk, 0, stream>>>(
            src12, E12, src23, E23, src34, E34, bcnt, N1, N2, NBKT);
        bucket_scan_kernel<<<1, 256, 0, stream>>>(bcnt, bbase, bcur, NBKT, Etot);
        csr_pass1_kernel<<<dim3((unsigned)((Etot + 256 * EPT - 1) / (256 * EPT))), blk, 0, stream>>>(
            src12, E12, src23, E23, src34, E34, bcur, recs, N1, N2, NBKT);
        csr_pass2_kernel<<<dim3((unsigned)NBKT), dim3(1024), 0, stream>>>(
            recs, bbase, offcnt, el, NT);
    }

    // ---- upward (MFMA MLPs, f16 intermediates) ----
    mlp_mfma_kernel<false><<<tiles(N1), blk, 0, stream>>>(feat, nullptr, WaT1, b1a, WbT1, b1b, h1, N1);
    mlp_mfma_kernel<true ><<<tiles(N2), blk, 0, stream>>>(h1, src12, WaT2, b2a, WbT2, b2b, h2t, N2);
    gather_sum_kernel<<<rowblk16(N1), blk, 0, stream>>>(h2t, offcnt, el, h2on1, N1);
    mlp_mfma_kernel<true ><<<tiles(N3), blk, 0, stream>>>(h2t, src23, WaT3, b3a, WbT3, b3b, h3t, N3);

    // ---- downward (all f16, fp32 accum; pre-resolved payloads) ----
    prod_gather_kernel<<<rowblk16(N3), blk, 0, stream>>>(h3t, offcnt + N1 + N2, el, h3dn, N3);
    gather_sum_kernel<<<rowblk16(N2), blk, 0, stream>>>(h3dn, offcnt + N1, el, h2dn, N2);
    gather_sum_kernel<<<rowblk16(N1), blk, 0, stream>>>(h2dn, offcnt, el, hdown, N1);

    // ---- final fused concat-linear + SiLU (f32 out) ----
    out_mfma_kernel<<<tiles(N1), blk, 0, stream>>>(h1, h2on1, hdown, WoT, bo, (float*)d_out, N1);
}

// Round 8
// 277.522 us; speedup vs baseline: 11.7788x; 1.0397x over previous
//
#include <hip/hip_runtime.h>

#define D 128
#define XSH 136   // f16 row stride (272 B = 16*17): 16B-aligned rows, spreads banks

#define SHIFT 11
#define NPB   2048            // nodes per bucket = 1 << SHIFT
#define EPT   8               // edges per thread in csr pass 1

typedef _Float16 f16;
typedef __attribute__((ext_vector_type(4))) _Float16 f16x4;
typedef __attribute__((ext_vector_type(8))) _Float16 f16x8;
typedef __attribute__((ext_vector_type(4))) float    f32x4;

__device__ __forceinline__ float silu_f(float x) {
    return x / (1.0f + __expf(-x));
}

// ---------------- weight pre-convert (all 7 weights in one launch) ----------------
struct WPtrs { const float* s0; const float* s1; const float* s2;
               const float* s3; const float* s4; const float* s5; };
__global__ void wconv_all_kernel(WPtrs wp, const float* __restrict__ Wo, f16* __restrict__ WT)
{
    const int blk = blockIdx.x, t = threadIdx.x;
    if (blk < 384) {
        const int wid = blk >> 6;
        const int off = ((blk & 63) << 8) + t;     // 0..16383
        const int n = off >> 7, k = off & 127;
        const float* s;
        switch (wid) {
            case 0: s = wp.s0; break;
            case 1: s = wp.s1; break;
            case 2: s = wp.s2; break;
            case 3: s = wp.s3; break;
            case 4: s = wp.s4; break;
            default: s = wp.s5; break;
        }
        WT[(wid << 14) + off] = (f16)s[(k << 7) + n];
    } else {
        const int off = ((blk - 384) << 8) + t;    // 0..49151 = n*384+k
        const int n = off / 384, k = off - n * 384;
        WT[(6 << 14) + off] = (f16)Wo[k * 128 + n];
    }
}

// ---------------- MLP via MFMA (swapped operands): out = silu(in@Wa+ba)@Wb+bb --------
// Block = 256 thr = 4 waves; block owns 64 rows; wave w owns output cols [32w,32w+32).
// mfma(W_frag, x_frag): lane holds OUTPUT row = lane&15 (within 16-row tile m),
// n = w*32 + nt*16 + (lane>>4)*4 + reg  -> packed f16x4 epilogue writes.
template<bool GATHER>
__launch_bounds__(256)
__global__ void mlp_mfma_kernel(const void* __restrict__ in_, const int* __restrict__ src,
                                const f16* __restrict__ WaT, const float* __restrict__ ba,
                                const f16* __restrict__ WbT, const float* __restrict__ bb,
                                f16* __restrict__ out, int nrows)
{
    __shared__ f16 xs[64][XSH];
    __shared__ f16 ys[64][XSH];
    const int t = threadIdx.x;
    const int w = t >> 6, l = t & 63;
    const int cl = l & 15, kg = l >> 4;
    const int row0 = blockIdx.x * 64;

    // ---- weight fragments -> registers (once per block) ----
    f16x8 wa[2][4], wb[2][4];
    #pragma unroll
    for (int nt = 0; nt < 2; ++nt)
        #pragma unroll
        for (int kk = 0; kk < 4; ++kk) {
            const size_t o = (size_t)((w * 2 + nt) * 16 + cl) * D + kk * 32 + kg * 8;
            wa[nt][kk] = *(const f16x8*)(WaT + o);
            wb[nt][kk] = *(const f16x8*)(WbT + o);
        }

    // ---- stage A: 64 rows -> xs (f16) ----
    {
        const int r = t >> 2, q = t & 3;
        const int g = row0 + r;
        f16* dst = &xs[r][q * 32];
        if (g < nrows) {
            if (GATHER) {
                const f16* in = (const f16*)in_;
                const int a = src[2 * g], b = src[2 * g + 1];
                const f16x8* pa = (const f16x8*)(in + (size_t)a * D + q * 32);
                const f16x8* pb = (const f16x8*)(in + (size_t)b * D + q * 32);
                #pragma unroll
                for (int i = 0; i < 4; ++i) {
                    f16x8 av = pa[i], bv = pb[i], hv;
                    #pragma unroll
                    for (int j = 0; j < 8; ++j) hv[j] = (f16)((float)av[j] * (float)bv[j]);
                    *(f16x8*)(dst + 8 * i) = hv;
                }
            } else {
                const float* in = (const float*)in_;
                const float4* p = (const float4*)(in + (size_t)g * D + q * 32);
                #pragma unroll
                for (int i = 0; i < 4; ++i) {
                    float4 v0 = p[2 * i], v1 = p[2 * i + 1];
                    f16x8 hv = {(f16)v0.x, (f16)v0.y, (f16)v0.z, (f16)v0.w,
                                (f16)v1.x, (f16)v1.y, (f16)v1.z, (f16)v1.w};
                    *(f16x8*)(dst + 8 * i) = hv;
                }
            }
        } else {
            f16x8 z = {};
            #pragma unroll
            for (int i = 0; i < 4; ++i) *(f16x8*)(dst + 8 * i) = z;
        }
    }
    __syncthreads();                                // bar 1

    f32x4 acc[2][4];

    // ---- stage B: y = silu(x @ Wa + ba) ----
    #pragma unroll
    for (int nt = 0; nt < 2; ++nt)
        #pragma unroll
        for (int m = 0; m < 4; ++m) acc[nt][m] = (f32x4){0.f, 0.f, 0.f, 0.f};
    #pragma unroll
    for (int m = 0; m < 4; ++m)
        #pragma unroll
        for (int kk = 0; kk < 4; ++kk) {
            const f16x8 a = *(const f16x8*)&xs[m * 16 + cl][kk * 32 + kg * 8];
            acc[0][m] = __builtin_amdgcn_mfma_f32_16x16x32_f16(wa[0][kk], a, acc[0][m], 0, 0, 0);
            acc[1][m] = __builtin_amdgcn_mfma_f32_16x16x32_f16(wa[1][kk], a, acc[1][m], 0, 0, 0);
        }
    // epilogue B -> ys (packed b64 writes): row = m*16+cl, n0 = w*32+nt*16+kg*4
    #pragma unroll
    for (int nt = 0; nt < 2; ++nt) {
        const int n0 = w * 32 + nt * 16 + kg * 4;
        const float4 bv = *(const float4*)&ba[n0];
        #pragma unroll
        for (int m = 0; m < 4; ++m) {
            f16x4 y;
            y[0] = (f16)silu_f(acc[nt][m][0] + bv.x);
            y[1] = (f16)silu_f(acc[nt][m][1] + bv.y);
            y[2] = (f16)silu_f(acc[nt][m][2] + bv.z);
            y[3] = (f16)silu_f(acc[nt][m][3] + bv.w);
            *(f16x4*)&ys[m * 16 + cl][n0] = y;
        }
    }
    __syncthreads();                                // bar 2

    // ---- stage C: z = y @ Wb + bb ----
    #pragma unroll
    for (int nt = 0; nt < 2; ++nt)
        #pragma unroll
        for (int m = 0; m < 4; ++m) acc[nt][m] = (f32x4){0.f, 0.f, 0.f, 0.f};
    #pragma unroll
    for (int m = 0; m < 4; ++m)
        #pragma unroll
        for (int kk = 0; kk < 4; ++kk) {
            const f16x8 a = *(const f16x8*)&ys[m * 16 + cl][kk * 32 + kg * 8];
            acc[0][m] = __builtin_amdgcn_mfma_f32_16x16x32_f16(wb[0][kk], a, acc[0][m], 0, 0, 0);
            acc[1][m] = __builtin_amdgcn_mfma_f32_16x16x32_f16(wb[1][kk], a, acc[1][m], 0, 0, 0);
        }
    #pragma unroll
    for (int nt = 0; nt < 2; ++nt) {
        const int n0 = w * 32 + nt * 16 + kg * 4;
        const float4 bv = *(const float4*)&bb[n0];
        #pragma unroll
        for (int m = 0; m < 4; ++m) {
            f16x4 z;
            z[0] = (f16)(acc[nt][m][0] + bv.x);
            z[1] = (f16)(acc[nt][m][1] + bv.y);
            z[2] = (f16)(acc[nt][m][2] + bv.z);
            z[3] = (f16)(acc[nt][m][3] + bv.w);
            *(f16x4*)&xs[m * 16 + cl][n0] = z;
        }
    }
    __syncthreads();                                // bar 3

    // ---- coalesced f16 store ----
    {
        const int r = t >> 2, q = t & 3;
        const int g = row0 + r;
        if (g < nrows) {
            f16* dst = out + (size_t)g * D + q * 32;
            #pragma unroll
            for (int i = 0; i < 4; ++i)
                *(f16x8*)(dst + 8 * i) = *(const f16x8*)&xs[r][q * 32 + 8 * i];
        }
    }
}

// ------------ final: out = silu(concat(h1,h2on1,hdown) @ Wo + bo), fp32 out ----------
// swapped operands -> direct float4 global stores (no LDS z roundtrip)
__launch_bounds__(256)
__global__ void out_mfma_kernel(const f16* __restrict__ h1, const f16* __restrict__ h2on1,
                                const f16* __restrict__ hdown,
                                const f16* __restrict__ WoT, const float* __restrict__ bo,
                                float* __restrict__ out, int nrows)
{
    __shared__ f16 xs[64][XSH];
    const int t = threadIdx.x;
    const int w = t >> 6, l = t & 63;
    const int cl = l & 15, kg = l >> 4;
    const int row0 = blockIdx.x * 64;

    f32x4 acc[2][4];
    #pragma unroll
    for (int nt = 0; nt < 2; ++nt)
        #pragma unroll
        for (int m = 0; m < 4; ++m) acc[nt][m] = (f32x4){0.f, 0.f, 0.f, 0.f};

    const f16* parts[3] = {h1, h2on1, hdown};
    #pragma unroll
    for (int p = 0; p < 3; ++p) {
        f16x8 wo[2][4];
        #pragma unroll
        for (int nt = 0; nt < 2; ++nt)
            #pragma unroll
            for (int kk = 0; kk < 4; ++kk)
                wo[nt][kk] = *(const f16x8*)(WoT + (size_t)((w * 2 + nt) * 16 + cl) * 384
                                             + p * D + kk * 32 + kg * 8);
        {
            const int r = t >> 2, q = t & 3;
            const int g = row0 + r;
            f16* dst = &xs[r][q * 32];
            if (g < nrows) {
                const f16x8* pp = (const f16x8*)(parts[p] + (size_t)g * D + q * 32);
                #pragma unroll
                for (int i = 0; i < 4; ++i) *(f16x8*)(dst + 8 * i) = pp[i];
            } else {
                f16x8 z = {};
                #pragma unroll
                for (int i = 0; i < 4; ++i) *(f16x8*)(dst + 8 * i) = z;
            }
        }
        __syncthreads();
        #pragma unroll
        for (int m = 0; m < 4; ++m)
            #pragma unroll
            for (int kk = 0; kk < 4; ++kk) {
                const f16x8 a = *(const f16x8*)&xs[m * 16 + cl][kk * 32 + kg * 8];
                acc[0][m] = __builtin_amdgcn_mfma_f32_16x16x32_f16(wo[0][kk], a, acc[0][m], 0, 0, 0);
                acc[1][m] = __builtin_amdgcn_mfma_f32_16x16x32_f16(wo[1][kk], a, acc[1][m], 0, 0, 0);
            }
        __syncthreads();
    }

    // direct float4 stores: row = row0+m*16+cl, n0 = w*32+nt*16+kg*4
    #pragma unroll
    for (int nt = 0; nt < 2; ++nt) {
        const int n0 = w * 32 + nt * 16 + kg * 4;
        const float4 bv = *(const float4*)&bo[n0];
        #pragma unroll
        for (int m = 0; m < 4; ++m) {
            const int g = row0 + m * 16 + cl;
            if (g < nrows) {
                float4 v = make_float4(silu_f(acc[nt][m][0] + bv.x),
                                       silu_f(acc[nt][m][1] + bv.y),
                                       silu_f(acc[nt][m][2] + bv.z),
                                       silu_f(acc[nt][m][3] + bv.w));
                *(float4*)(out + (size_t)g * D + n0) = v;
            }
        }
    }
}

// ================= bucketed reverse-CSR build =================
__global__ void bucket_hist_kernel(const int* __restrict__ s12, int E12,
                                   const int* __restrict__ s23, int E23,
                                   const int* __restrict__ s34, int E34,
                                   int* __restrict__ bcnt, int N1, int N2, int nbkt)
{
    __shared__ int h[256];
    const int t = threadIdx.x;
    for (int i = t; i < 256; i += blockDim.x) h[i] = 0;
    __syncthreads();
    const int Etot = E12 + E23 + E34;
    for (int g = blockIdx.x * blockDim.x + t; g < Etot; g += gridDim.x * blockDim.x) {
        int node;
        if (g < E12) node = s12[g];
        else if (g < E12 + E23) node = N1 + s23[g - E12];
        else node = N1 + N2 + s34[g - E12 - E23];
        atomicAdd(&h[node >> SHIFT], 1);
    }
    __syncthreads();
    for (int i = t; i < nbkt; i += blockDim.x)
        if (h[i]) atomicAdd(&bcnt[i], h[i]);
}

__global__ void bucket_scan_kernel(const int* __restrict__ bcnt, int* __restrict__ bbase,
                                   int* __restrict__ bcur, int nbkt, int Etot)
{
    __shared__ int s[256];
    const int t = threadIdx.x;
    const int v = (t < nbkt) ? bcnt[t] : 0;
    s[t] = v;
    __syncthreads();
    for (int d = 1; d < 256; d <<= 1) {
        const int u = (t >= d) ? s[t - d] : 0;
        __syncthreads();
        s[t] += u;
        __syncthreads();
    }
    if (t < nbkt) { const int ex = s[t] - v; bbase[t] = ex; bcur[t] = ex; }
    if (t == 0) bbase[nbkt] = Etot;
}

__global__ void csr_pass1_kernel(const int* __restrict__ s12, int E12,
                                 const int* __restrict__ s23, int E23,
                                 const int* __restrict__ s34, int E34,
                                 int* __restrict__ bcur, int2* __restrict__ recs,
                                 int N1, int N2, int nbkt)
{
    __shared__ int cnt[256];
    __shared__ int gbase[256];
    const int t = threadIdx.x;
    const int chunk = blockIdx.x * (256 * EPT);
    const int Etot = E12 + E23 + E34;
    for (int i = t; i < 256; i += 256) cnt[i] = 0;
    __syncthreads();
    int node_[EPT], pay_[EPT], br_[EPT];
    #pragma unroll
    for (int i = 0; i < EPT; ++i) {
        const int g = chunk + i * 256 + t;
        int node = -1, pay = 0, b = 0, r = 0;
        if (g < Etot) {
            if (g < E12) { node = s12[g]; pay = g >> 1; }
            else if (g < E12 + E23) { const int e = g - E12; node = N1 + s23[e]; pay = e >> 1; }
            else { const int e = g - E12 - E23; node = N1 + N2 + s34[e]; pay = s34[e ^ 1]; }
            b = node >> SHIFT;
            r = atomicAdd(&cnt[b], 1);
        }
        node_[i] = node; pay_[i] = pay; br_[i] = (b << 16) | r;
    }
    __syncthreads();
    if (t < nbkt && cnt[t]) gbase[t] = atomicAdd(&bcur[t], cnt[t]);
    __syncthreads();
    #pragma unroll
    for (int i = 0; i < EPT; ++i) {
        if (node_[i] >= 0) {
            const int b = br_[i] >> 16, r = br_[i] & 0xffff;
            recs[gbase[b] + r] = make_int2(node_[i], pay_[i]);
        }
    }
}

__launch_bounds__(1024)
__global__ void csr_pass2_kernel(const int2* __restrict__ recs,
                                 const int* __restrict__ bbase,
                                 int2* __restrict__ offcnt, int* __restrict__ el, int NT)
{
    __shared__ int cnt2[NPB];
    __shared__ int pref[NPB];
    __shared__ int s1[NPB / 2];
    const int b = blockIdx.x, t = threadIdx.x;     // blockDim = 1024 = NPB/2
    const int node0 = b << SHIFT;
    const int k0 = bbase[b], k1 = bbase[b + 1];
    for (int i = t; i < NPB; i += 1024) cnt2[i] = 0;
    __syncthreads();
    for (int k = k0 + t; k < k1; k += 1024)
        atomicAdd(&cnt2[recs[k].x - node0], 1);
    __syncthreads();
    s1[t] = cnt2[2 * t] + cnt2[2 * t + 1];
    __syncthreads();
    for (int d = 1; d < 1024; d <<= 1) {
        const int u = (t >= d) ? s1[t - d] : 0;
        __syncthreads();
        s1[t] += u;
        __syncthreads();
    }
    {
        const int a = cnt2[2 * t];
        const int pairsum = a + cnt2[2 * t + 1];
        const int ex0 = s1[t] - pairsum;
        pref[2 * t] = ex0;
        pref[2 * t + 1] = ex0 + a;
    }
    __syncthreads();
    for (int i = t; i < NPB; i += 1024) {
        const int node = node0 + i;
        if (node < NT) offcnt[node] = make_int2(k0 + pref[i], cnt2[i]);
    }
    __syncthreads();
    for (int k = k0 + t; k < k1; k += 1024) {
        const int2 r = recs[k];
        const int pos = atomicAdd(&pref[r.x - node0], 1);
        el[k0 + pos] = r.y;
    }
}

// ---- h3dn[i] = h3t[i] * sum of h3t[sibling] (payload = sibling index), f16 out ----
__global__ void prod_gather_kernel(const f16* __restrict__ h3t,
                                   const int2* __restrict__ offcnt,
                                   const int* __restrict__ el,
                                   f16* __restrict__ h3dn, int nrows)
{
    const long long g = (long long)blockIdx.x * blockDim.x + threadIdx.x;
    const int i = (int)(g >> 4);
    if (i >= nrows) return;
    const int c = ((int)g & 15) * 8;
    const f16x8 ownv = *(const f16x8*)(h3t + (size_t)i * D + c);
    float acc0[8] = {}, acc1[8] = {};
    const int2 oc = offcnt[i];
    const int base = oc.x, deg = oc.y;
    int d = 0;
    for (; d + 4 <= deg; d += 4) {
        const int s0 = el[base + d + 0], s1v = el[base + d + 1];
        const int s2 = el[base + d + 2], s3v = el[base + d + 3];
        const f16x8 v0 = *(const f16x8*)(h3t + (size_t)s0 * D + c);
        const f16x8 v1 = *(const f16x8*)(h3t + (size_t)s1v * D + c);
        const f16x8 v2 = *(const f16x8*)(h3t + (size_t)s2 * D + c);
        const f16x8 v3 = *(const f16x8*)(h3t + (size_t)s3v * D + c);
        #pragma unroll
        for (int j = 0; j < 8; ++j) {
            acc0[j] += (float)v0[j] + (float)v2[j];
            acc1[j] += (float)v1[j] + (float)v3[j];
        }
    }
    for (; d < deg; ++d) {
        const int s0 = el[base + d];
        const f16x8 v0 = *(const f16x8*)(h3t + (size_t)s0 * D + c);
        #pragma unroll
        for (int j = 0; j < 8; ++j) acc0[j] += (float)v0[j];
    }
    f16x8 r;
    #pragma unroll
    for (int j = 0; j < 8; ++j) r[j] = (f16)((acc0[j] + acc1[j]) * (float)ownv[j]);
    *(f16x8*)(h3dn + (size_t)i * D + c) = r;
}

// ---- dst[i] = sum of val[payload] over CSR entries (f16 in/out, fp32 accum) ----
__global__ void gather_sum_kernel(const f16* __restrict__ val,
                                  const int2* __restrict__ offcnt,
                                  const int* __restrict__ el,
                                  f16* __restrict__ dst, int nrows)
{
    const long long g = (long long)blockIdx.x * blockDim.x + threadIdx.x;
    const int i = (int)(g >> 4);
    if (i >= nrows) return;
    const int c = ((int)g & 15) * 8;
    float acc0[8] = {}, acc1[8] = {};
    const int2 oc = offcnt[i];
    const int base = oc.x, deg = oc.y;
    int d = 0;
    for (; d + 4 <= deg; d += 4) {
        const int s0 = el[base + d + 0], s1v = el[base + d + 1];
        const int s2 = el[base + d + 2], s3v = el[base + d + 3];
        const f16x8 v0 = *(const f16x8*)(val + (size_t)s0 * D + c);
        const f16x8 v1 = *(const f16x8*)(val + (size_t)s1v * D + c);
        const f16x8 v2 = *(const f16x8*)(val + (size_t)s2 * D + c);
        const f16x8 v3 = *(const f16x8*)(val + (size_t)s3v * D + c);
        #pragma unroll
        for (int j = 0; j < 8; ++j) {
            acc0[j] += (float)v0[j] + (float)v2[j];
            acc1[j] += (float)v1[j] + (float)v3[j];
        }
    }
    for (; d < deg; ++d) {
        const int s0 = el[base + d];
        const f16x8 v0 = *(const f16x8*)(val + (size_t)s0 * D + c);
        #pragma unroll
        for (int j = 0; j < 8; ++j) acc0[j] += (float)v0[j];
    }
    f16x8 r;
    #pragma unroll
    for (int j = 0; j < 8; ++j) r[j] = (f16)(acc0[j] + acc1[j]);
    *(f16x8*)(dst + (size_t)i * D + c) = r;
}

// diagnostic: if workspace too small, report its size via d_out[0]
__global__ void ws_report_kernel(float* out, float v) {
    if (threadIdx.x == 0 && blockIdx.x == 0) out[0] = v;
}

extern "C" void kernel_launch(void* const* d_in, const int* in_sizes, int n_in,
                              void* d_out, int out_size, void* d_ws, size_t ws_size,
                              hipStream_t stream)
{
    const float* feat = (const float*)d_in[0];
    const float* W1a = (const float*)d_in[1];  const float* b1a = (const float*)d_in[2];
    const float* W1b = (const float*)d_in[3];  const float* b1b = (const float*)d_in[4];
    const float* W2a = (const float*)d_in[5];  const float* b2a = (const float*)d_in[6];
    const float* W2b = (const float*)d_in[7];  const float* b2b = (const float*)d_in[8];
    const float* W3a = (const float*)d_in[9];  const float* b3a = (const float*)d_in[10];
    const float* W3b = (const float*)d_in[11]; const float* b3b = (const float*)d_in[12];
    const float* Wo  = (const float*)d_in[13]; const float* bo  = (const float*)d_in[14];
    const int* src12 = (const int*)d_in[15];
    const int* src23 = (const int*)d_in[17];
    const int* src34 = (const int*)d_in[19];

    const int N1 = in_sizes[0] / D;
    const int N2 = in_sizes[15] / 2;
    const int N3 = in_sizes[17] / 2;
    const int N4 = in_sizes[19] / 2;
    const int E12 = 2 * N2, E23 = 2 * N3, E34 = 2 * N4;
    const int NT = N1 + N2 + N3;
    const int Etot = E12 + E23 + E34;
    const int NBKT = (NT + NPB - 1) >> SHIFT;

    // ---- workspace layout ----
    char* p = (char*)d_ws;
    f16* h1    = (f16*)p;  p += (size_t)N1 * D * sizeof(f16);
    f16* h2on1 = (f16*)p;  p += (size_t)N1 * D * sizeof(f16);
    f16* h2t   = (f16*)p;  p += (size_t)N2 * D * sizeof(f16);
    f16* h3t   = (f16*)p;  f16* h2dn  = h3t;    // alias: h3t dead after prod_gather
    p += (size_t)N3 * D * sizeof(f16);
    f16* h3dn  = (f16*)p;  f16* hdown = h3dn;   // alias: h3dn dead after h2dn gather
    p += (size_t)N3 * D * sizeof(f16);

    p = (char*)(((uintptr_t)p + 15) & ~(uintptr_t)15);
    int2* offcnt = (int2*)p;             p += (size_t)NT * sizeof(int2);
    int2* recs   = (int2*)p;             p += (size_t)Etot * sizeof(int2);
    int*  el     = (int*)p;              p += (size_t)Etot * sizeof(int);
    int*  bcnt   = (int*)p;              p += 256 * sizeof(int);
    int*  bbase  = (int*)p;              p += 257 * sizeof(int);
    int*  bcur   = (int*)p;              p += 256 * sizeof(int);

    p = (char*)(((uintptr_t)p + 31) & ~(uintptr_t)31);
    f16* WT = (f16*)p;
    f16* WaT1 = WT;
    f16* WbT1 = WaT1 + D * D;
    f16* WaT2 = WbT1 + D * D;
    f16* WbT2 = WaT2 + D * D;
    f16* WaT3 = WbT2 + D * D;
    f16* WbT3 = WaT3 + D * D;
    f16* WoT  = WbT3 + D * D;
    p = (char*)(WoT + 384 * D);

    const size_t need = p - (char*)d_ws;
    if (ws_size < need || NBKT > 256) {
        ws_report_kernel<<<1, 64, 0, stream>>>((float*)d_out, (float)ws_size);
        return;
    }

    dim3 blk(256);
    auto tiles    = [](int n) { return dim3((unsigned)((n + 63) / 64)); };
    auto rowblk16 = [](long long rows) { return dim3((unsigned)((rows * 16 + 255) / 256)); };

    // ---- weight convert: one launch ----
    WPtrs wp = {W1a, W1b, W2a, W2b, W3a, W3b};
    wconv_all_kernel<<<dim3(576), blk, 0, stream>>>(wp, Wo, WT);

    // ---- bucketed CSR build ----
    hipMemsetAsync(bcnt, 0, 256 * sizeof(int), stream);
    {
        const int nblk = (Etot + 2047) / 2048;
        bucket_hist_kernel<<<dim3((unsigned)nblk), blk, 0, stream>>>(
            src12, E12, src23, E23, src34, E34, bcnt, N1, N2, NBKT);
        bucket_scan_kernel<<<1, 256, 0, stream>>>(bcnt, bbase, bcur, NBKT, Etot);
        csr_pass1_kernel<<<dim3((unsigned)((Etot + 256 * EPT - 1) / (256 * EPT))), blk, 0, stream>>>(
            src12, E12, src23, E23, src34, E34, bcur, recs, N1, N2, NBKT);
        csr_pass2_kernel<<<dim3((unsigned)NBKT), dim3(1024), 0, stream>>>(
            recs, bbase, offcnt, el, NT);
    }

    // ---- upward (MFMA MLPs, f16 intermediates) ----
    mlp_mfma_kernel<false><<<tiles(N1), blk, 0, stream>>>(feat, nullptr, WaT1, b1a, WbT1, b1b, h1, N1);
    mlp_mfma_kernel<true ><<<tiles(N2), blk, 0, stream>>>(h1, src12, WaT2, b2a, WbT2, b2b, h2t, N2);
    gather_sum_kernel<<<rowblk16(N1), blk, 0, stream>>>(h2t, offcnt, el, h2on1, N1);
    mlp_mfma_kernel<true ><<<tiles(N3), blk, 0, stream>>>(h2t, src23, WaT3, b3a, WbT3, b3b, h3t, N3);

    // ---- downward (all f16, fp32 accum; pre-resolved payloads) ----
    prod_gather_kernel<<<rowblk16(N3), blk, 0, stream>>>(h3t, offcnt + N1 + N2, el, h3dn, N3);
    gather_sum_kernel<<<rowblk16(N2), blk, 0, stream>>>(h3dn, offcnt + N1, el, h2dn, N2);
    gather_sum_kernel<<<rowblk16(N1), blk, 0, stream>>>(h2dn, offcnt, el, hdown, N1);

    // ---- final fused concat-linear + SiLU (f32 out) ----
    out_mfma_kernel<<<tiles(N1), blk, 0, stream>>>(h1, h2on1, hdown, WoT, bo, (float*)d_out, N1);
}